// Round 10
// baseline (347.149 us; speedup 1.0000x reference)
//
#include <hip/hip_runtime.h>
#include <hip/hip_cooperative_groups.h>
#include <math.h>

namespace cg = cooperative_groups;

#define Bg   32
#define NPGc 2048
#define Nn   (Bg*NPGc)      // 65536
#define DEGc 8
#define Ee   (Nn*DEGc)      // 524288
#define INc  64
#define H1c  128
#define H2c  256
#define K1c  1024
#define K2c  512
#define N1c  (Bg*K1c)       // 32768
#define N2c  (Bg*K2c)       // 16384
#define SLAB 64             // fixed CSR slab per node

typedef __attribute__((ext_vector_type(8))) short short8;
typedef __attribute__((ext_vector_type(4))) float f32x4;

__device__ __forceinline__ ushort f2bf(float f) {
    uint u = __float_as_uint(f);
    uint r = (u + 0x7fffu + ((u >> 16) & 1u)) >> 16;
    return (ushort)r;
}
__device__ __forceinline__ float bf2f(ushort v) { return __uint_as_float((uint)v << 16); }
__device__ __forceinline__ float bfhi(uint v) { return __uint_as_float(v & 0xffff0000u); }
__device__ __forceinline__ float bflo(uint v) { return __uint_as_float(v << 16); }
__device__ __forceinline__ uint fkey(float f) {
    uint u = __float_as_uint(f);
    return u ^ ((uint)((int)u >> 31) | 0x80000000u);
}
__device__ __forceinline__ void unpk8(uint4 v, float* f) {
    f[0] = bflo(v.x); f[1] = bfhi(v.x);
    f[2] = bflo(v.y); f[3] = bfhi(v.y);
    f[4] = bflo(v.z); f[5] = bfhi(v.z);
    f[6] = bflo(v.w); f[7] = bfhi(v.w);
}
__device__ __forceinline__ uint4 pack8(const float* a, float inv) {
    uint4 o;
    o.x = (uint)f2bf(a[0] * inv) | ((uint)f2bf(a[1] * inv) << 16);
    o.y = (uint)f2bf(a[2] * inv) | ((uint)f2bf(a[3] * inv) << 16);
    o.z = (uint)f2bf(a[4] * inv) | ((uint)f2bf(a[5] * inv) << 16);
    o.w = (uint)f2bf(a[6] * inv) | ((uint)f2bf(a[7] * inv) << 16);
    return o;
}
__device__ __forceinline__ void accf8(float* a, const float* p) {
    float4 u0 = *(const float4*)p;
    float4 u1 = *(const float4*)(p + 4);
    a[0] += u0.x; a[1] += u0.y; a[2] += u0.z; a[3] += u0.w;
    a[4] += u1.x; a[5] += u1.y; a[6] += u1.z; a[7] += u1.w;
}

// ---------------- init: zero wc1/stats/pooled ----------------
__global__ void init_kernel(int4* __restrict__ wc1, int4* __restrict__ dstats,
                            int4* __restrict__ pooled) {
    int id = blockIdx.x * blockDim.x + threadIdx.x;
    int4 z = {0, 0, 0, 0};
    if (id < 16384) { wc1[id] = z; return; }
    id -= 16384;
    if (id < 384)   { dstats[id] = z; return; }
    id -= 384;
    if (id < 2048)  { pooled[id] = z; }
}
#define INIT_TOTAL (16384 + 384 + 2048)

// ------- prep2: fill1 (slab CSR) || weight transposes, grid-partitioned -------
__global__ void prep2_kernel(const int* __restrict__ src, const int* __restrict__ tgt,
                             const float* __restrict__ W1l, const float* __restrict__ W1r,
                             const float* __restrict__ W2l, const float* __restrict__ W2r,
                             ushort* __restrict__ T1l, ushort* __restrict__ T1r,
                             ushort* __restrict__ T2l, ushort* __restrict__ T2r,
                             int* __restrict__ wc1, int* __restrict__ col1) {
    int id = blockIdx.x * blockDim.x + threadIdx.x;
    if (id < Ee) {
        int t = tgt[id];
        int p = atomicAdd(&wc1[t], 1);
        col1[t * SLAB + p] = src[id];
        return;
    }
    id -= Ee;
    if (id < 8192) {
        int c = id / 64, k = id % 64;
        T1l[id] = f2bf(W1l[k * 128 + c]);
        T1r[id] = f2bf(W1r[k * 128 + c]);
        return;
    }
    id -= 8192;
    if (id < 32768) {
        int c = id / 128, k = id % 128;
        T2l[id] = f2bf(W2l[k * 256 + c]);
        T2r[id] = f2bf(W2r[k * 256 + c]);
    }
}
#define PREP2_TOTAL (Ee + 8192 + 32768)

// ---- gemm1f: fused agg1 + SAGEConv1 GEMM from f32 x, full-K staged, 1 barrier ----
__global__ __launch_bounds__(512) void gemm1f_kernel(
        const float* __restrict__ x, const int* __restrict__ deg,
        const int* __restrict__ col, const ushort* __restrict__ Wtl,
        const ushort* __restrict__ Wtr, const float* __restrict__ bias,
        ushort* __restrict__ out, double* __restrict__ dsum,
        double* __restrict__ dsq) {
    __shared__ ushort As[2][2][128][36];   // [src][kt][row][ch]
    __shared__ ushort Bs[2][2][128][36];   // full B
    __shared__ float bsumS[2][128], bsqS[2][128];
    int b = blockIdx.x;
    int bs = ((b & 7) << 6) + (b >> 3);
    int m0 = bs << 7;
    int lane = threadIdx.x & 63;
    int wid = threadIdx.x >> 6;
    int wr = (wid & 1) << 6, wc = (wid >> 1) << 5;
    int l16 = lane & 15, quad = lane >> 4;

    int ar = threadIdx.x >> 2, ack = (threadIdx.x & 3) * 8;
    int anode = m0 + ar;
    int abg = anode * SLAB, adg = deg[anode];
    int4 c0h = *(const int4*)&col[abg];
    int4 c1h = *(const int4*)&col[abg + 4];
    int anb[8] = {c0h.x, c0h.y, c0h.z, c0h.w, c1h.x, c1h.y, c1h.z, c1h.w};

    {   // B full stage
        int r = threadIdx.x >> 2, ck = (threadIdx.x & 3) * 8;
#pragma unroll
        for (int kt = 0; kt < 2; kt++) {
            *(uint4*)&Bs[0][kt][r][ck] = *(const uint4*)&Wtl[(size_t)r * INc + kt * 32 + ck];
            *(uint4*)&Bs[1][kt][r][ck] = *(const uint4*)&Wtr[(size_t)r * INc + kt * 32 + ck];
        }
    }
    {   // A own row (f32 -> bf16), both k-slices
#pragma unroll
        for (int kt = 0; kt < 2; kt++) {
            const float* xp = &x[(size_t)anode * INc + kt * 32 + ack];
            float vals[8];
            float4 v0 = *(const float4*)xp, v1 = *(const float4*)(xp + 4);
            vals[0] = v0.x; vals[1] = v0.y; vals[2] = v0.z; vals[3] = v0.w;
            vals[4] = v1.x; vals[5] = v1.y; vals[6] = v1.z; vals[7] = v1.w;
            *(uint4*)&As[1][kt][ar][ack] = pack8(vals, 1.f);
        }
    }
    {   // A agg: all neighbor gathers up front, both k-slices
        float aacc[2][8];
#pragma unroll
        for (int kt = 0; kt < 2; kt++)
#pragma unroll
            for (int q = 0; q < 8; q++) aacc[kt][q] = 0.f;
#pragma unroll
        for (int j = 0; j < 8; j++)
            if (j < adg) {
                const float* xp = &x[(size_t)anb[j] * INc + ack];
#pragma unroll
                for (int kt = 0; kt < 2; kt++) accf8(aacc[kt], xp + kt * 32);
            }
        for (int i = abg + 8; i < abg + adg; i++) {
            const float* xp = &x[(size_t)col[i] * INc + ack];
#pragma unroll
            for (int kt = 0; kt < 2; kt++) accf8(aacc[kt], xp + kt * 32);
        }
        int cdg = adg < 1 ? 1 : adg;
        float inv = 1.f / (float)cdg;
#pragma unroll
        for (int kt = 0; kt < 2; kt++)
            *(uint4*)&As[0][kt][ar][ack] = pack8(aacc[kt], inv);
    }
    __syncthreads();

    f32x4 acc[4][2];
#pragma unroll
    for (int a = 0; a < 4; a++)
#pragma unroll
        for (int c = 0; c < 2; c++) acc[a][c] = (f32x4){0.f, 0.f, 0.f, 0.f};

#pragma unroll
    for (int kt = 0; kt < 2; kt++) {
        short8 a[2][4], bfr[2][2];
#pragma unroll
        for (int s = 0; s < 2; s++)
#pragma unroll
            for (int mt = 0; mt < 4; mt++)
                a[s][mt] = *(const short8*)&As[s][kt][wr + mt * 16 + l16][quad * 8];
#pragma unroll
        for (int s = 0; s < 2; s++)
#pragma unroll
            for (int nt = 0; nt < 2; nt++)
                bfr[s][nt] = *(const short8*)&Bs[s][kt][wc + nt * 16 + l16][quad * 8];
#pragma unroll
        for (int mt = 0; mt < 4; mt++)
#pragma unroll
            for (int nt = 0; nt < 2; nt++) {
                acc[mt][nt] = __builtin_amdgcn_mfma_f32_16x16x32_bf16(
                    a[0][mt], bfr[0][nt], acc[mt][nt], 0, 0, 0);
                acc[mt][nt] = __builtin_amdgcn_mfma_f32_16x16x32_bf16(
                    a[1][mt], bfr[1][nt], acc[mt][nt], 0, 0, 0);
            }
    }
    float s[2] = {0.f, 0.f}, sq[2] = {0.f, 0.f};
#pragma unroll
    for (int nt = 0; nt < 2; nt++) {
        int colx = wc + nt * 16 + l16;
        float bv = bias[colx];
#pragma unroll
        for (int mt = 0; mt < 4; mt++)
#pragma unroll
            for (int rr = 0; rr < 4; rr++) {
                int row = m0 + wr + mt * 16 + quad * 4 + rr;
                float ov = acc[mt][nt][rr] + bv;
                out[(size_t)row * H1c + colx] = f2bf(ov);
                s[nt] += ov; sq[nt] += ov * ov;
            }
    }
#pragma unroll
    for (int nt = 0; nt < 2; nt++) {
        float ss = s[nt], qq = sq[nt];
        ss += __shfl_down(ss, 16); qq += __shfl_down(qq, 16);
        ss += __shfl_down(ss, 32); qq += __shfl_down(qq, 32);
        if (quad == 0) {
            bsumS[wid & 1][wc + nt * 16 + l16] = ss;
            bsqS[wid & 1][wc + nt * 16 + l16] = qq;
        }
    }
    __syncthreads();
    if (threadIdx.x < 128) {
        int c = threadIdx.x;
        atomicAdd(&dsum[c], (double)(bsumS[0][c] + bsumS[1][c]));
        atomicAdd(&dsq[c], (double)(bsqS[0][c] + bsqS[1][c]));
    }
}

// ------- score1: full-grid, 8 lanes/node, uint4 loads, 3-step group reduce -------
template<int C>
__global__ __launch_bounds__(256) void score_kernel(const ushort* __restrict__ h,
                                                    const double* __restrict__ dsum,
                                                    const double* __restrict__ dsq,
                                                    const float* __restrict__ g,
                                                    const float* __restrict__ b,
                                                    const float* __restrict__ wrel,
                                                    const float* __restrict__ wroot,
                                                    float* __restrict__ r,
                                                    float* __restrict__ root, int n) {
    __shared__ float sc[C], sh[C], wrl[C], wrt[C];
    if ((int)threadIdx.x < C) {
        int c = threadIdx.x;
        double m = dsum[c] / (double)n;
        double var = dsq[c] / (double)n - m * m;
        float s = g[c] * (float)(1.0 / sqrt(var + 1e-5));
        sc[c] = s; sh[c] = b[c] - (float)m * s;
        wrl[c] = wrel[c]; wrt[c] = wroot[c];
    }
    __syncthreads();
    int gid = blockIdx.x * 256 + threadIdx.x;
    int node = gid >> 3, ln = gid & 7;
    float rr = 0.f, rt = 0.f;
#pragma unroll
    for (int p = 0; p < C / 64; p++) {
        int cb = p * 64 + ln * 8;
        uint4 v = *(const uint4*)&h[(size_t)node * C + cb];
        float vv[8];
        unpk8(v, vv);
#pragma unroll
        for (int q = 0; q < 8; q++) {
            int cc = cb + q;
            float val = fmaxf(vv[q] * sc[cc] + sh[cc], 0.f);
            rr += val * wrl[cc];
            rt += val * wrt[cc];
        }
    }
#pragma unroll
    for (int off = 4; off; off >>= 1) {
        rr += __shfl_down(rr, off);
        rt += __shfl_down(rt, off);
    }
    if (ln == 0) { r[node] = rr; root[node] = rt; }
}

// ---- sel1: LDS r-slice + svals + radix select + perm/tv + fused layer2 CSR build ----
__global__ void __launch_bounds__(1024) sel1_kernel(const float* __restrict__ r,
                                                    const float* __restrict__ root,
                                                    const int* __restrict__ deg,
                                                    const int* __restrict__ col,
                                                    const float* __restrict__ brel,
                                                    int* __restrict__ perm,
                                                    float* __restrict__ tval,
                                                    int* __restrict__ wc2,
                                                    int* __restrict__ col2) {
    __shared__ float rL[2048];
    __shared__ float svals[2048];
    __shared__ uint hist[257];
    __shared__ uint wsum[16];
    __shared__ uint s_b, s_rem;
    __shared__ int mapL[2048];
    __shared__ int oldL[1024];
    int g = blockIdx.x;
    int tid = threadIdx.x;
    int lane = tid & 63, wid = tid >> 6;
    int base = g * NPGc;
    rL[tid] = r[base + tid];
    rL[tid + 1024] = r[base + tid + 1024];
    if (tid < 257) hist[tid] = 0;
    __syncthreads();
    float bv = brel[0];
#pragma unroll
    for (int j = 0; j < 2; j++) {
        int i = tid + (j << 10);
        int node = base + i;
        float acc = bv + root[node];
        int e0 = node * SLAB, dg = deg[node];
        int4 c0 = *(const int4*)&col[e0];
        int4 c1 = *(const int4*)&col[e0 + 4];
        int nb[8] = {c0.x, c0.y, c0.z, c0.w, c1.x, c1.y, c1.z, c1.w};
#pragma unroll
        for (int q = 0; q < 8; q++)
            if (q < dg) acc += rL[nb[q] - base];
        for (int e = e0 + 8; e < e0 + dg; e++) acc += rL[col[e] - base];
        svals[i] = acc;
    }
    __syncthreads();

    uint prefix = 0, himask = 0, rem = (uint)K1c;
    for (int shift = 24; shift >= 0; shift -= 8) {
#pragma unroll
        for (int j = 0; j < 2; j++) {
            uint kk = fkey(svals[tid + (j << 10)]);
            if ((kk & himask) == prefix) atomicAdd(&hist[(kk >> shift) & 255], 1);
        }
        __syncthreads();
        if (tid < 64) {
            int L = tid;
            uint h0 = hist[4 * L], h1v = hist[4 * L + 1], h2v = hist[4 * L + 2],
                 h3 = hist[4 * L + 3];
            uint s3 = h3, s2 = h2v + s3, s1 = h1v + s2, s0 = h0 + s1;
            uint v = s0;
            for (int off = 1; off < 64; off <<= 1) {
                uint u = __shfl_down(v, off);
                if (L + off < 64) v += u;
            }
            uint above = v - s0;
            hist[4 * L] = s0 + above;
            hist[4 * L + 1] = s1 + above;
            hist[4 * L + 2] = s2 + above;
            hist[4 * L + 3] = s3 + above;
        }
        __syncthreads();
        if (tid < 256) {
            uint sb = hist[tid], sb1 = hist[tid + 1];
            if (sb >= rem && sb1 < rem) { s_b = (uint)tid; s_rem = rem - sb1; }
        }
        __syncthreads();
        prefix |= (s_b << shift);
        rem = s_rem;
        himask |= (0xFFu << shift);
        if (tid < 256) hist[tid] = 0;
        __syncthreads();
    }
    uint thr = prefix;
    uint tieM = rem;
    uint gcnt = 0, ecnt = 0, gflags = 0, eflags = 0;
#pragma unroll
    for (int j = 0; j < 2; j++) {
        uint kk = fkey(svals[tid + (j << 10)]);
        if (kk > thr) { gflags |= 1u << j; gcnt++; }
        else if (kk == thr) { eflags |= 1u << j; ecnt++; }
    }
    uint key = (gcnt << 16) | ecnt;
    uint v = key;
    for (int off = 1; off < 64; off <<= 1) {
        uint u = __shfl_up(v, off);
        if (lane >= off) v += u;
    }
    if (lane == 63) wsum[wid] = v;
    __syncthreads();
    if (tid < 16) {
        uint w0 = wsum[tid], w = w0;
        for (int off = 1; off < 16; off <<= 1) {
            uint u = __shfl_up(w, off);
            if ((int)tid >= off) w += u;
        }
        wsum[tid] = w - w0;
    }
    __syncthreads();
    uint excl = (v - key) + wsum[wid];
    uint gbase = excl >> 16, ebase = excl & 0xFFFFu;
#pragma unroll
    for (int j = 0; j < 2; j++) {
        bool gt = (gflags >> j) & 1u;
        bool eq = (eflags >> j) & 1u;
        int i = tid + (j << 10);
        int o = -1;
        if (gt || (eq && ebase < tieM)) {
            uint pos = gbase + min(ebase, tieM);
            o = g * K1c + (int)pos;
            perm[o] = base + i;
            tval[o] = tanhf(svals[i]);
            oldL[pos] = i;
        }
        mapL[i] = o;
        gbase += gt ? 1u : 0u;
        ebase += eq ? 1u : 0u;
    }
    __syncthreads();
    // fused nofill2: thread p handles kept position p
    {
        int p = tid;
        int i = oldL[p];
        int node = base + i;
        int e0 = node * SLAB, dg = deg[node];
        int4 cc0 = *(const int4*)&col[e0];
        int4 cc1 = *(const int4*)&col[e0 + 4];
        int nb[8] = {cc0.x, cc0.y, cc0.z, cc0.w, cc1.x, cc1.y, cc1.z, cc1.w};
        int cnt = 0;
        int newid = g * K1c + p;
        int ob = newid * SLAB;
#pragma unroll
        for (int q = 0; q < 8; q++)
            if (q < dg) {
                int m = mapL[nb[q] - base];
                if (m >= 0) col2[ob + cnt++] = m;
            }
        for (int e = e0 + 8; e < e0 + dg; e++) {
            int m = mapL[col[e] - base];
            if (m >= 0) col2[ob + cnt++] = m;
        }
        wc2[newid] = cnt;
    }
}

// ---- gemm2s: cooperative mega — GEMM2 + BN2 stats + score2 + select + pool + readout ----
__global__ __launch_bounds__(512) void gemm2s_kernel(
        const ushort* __restrict__ h1, const int* __restrict__ perm1,
        const float* __restrict__ tv1, const double* __restrict__ dsum1,
        const double* __restrict__ dsq1, const float* __restrict__ bn1g,
        const float* __restrict__ bn1b, const int* __restrict__ deg,
        const int* __restrict__ col, const ushort* __restrict__ Wtl,
        const ushort* __restrict__ Wtr, const float* __restrict__ bias,
        double* __restrict__ dsum, double* __restrict__ dsq,
        const float* __restrict__ bn2g, const float* __restrict__ bn2b,
        const float* __restrict__ wrel, const float* __restrict__ wroot,
        const float* __restrict__ brel, float* __restrict__ r2,
        float* __restrict__ root2, float* __restrict__ tvflag,
        float* __restrict__ pooled, const float* __restrict__ Wlin,
        const float* __restrict__ blin, float* __restrict__ out) {
    __shared__ ushort As[2][4][128][36];       // 73.7 KB
    __shared__ ushort Bs[2][2][256][36];       // 73.7 KB (reused by later phases)
    __shared__ float bsumS[2][256], bsqS[2][256];
    __shared__ float sc1[128], sh1[128];
    __shared__ float sc2S[256], shfS[256];
    cg::grid_group grid = cg::this_grid();

    int b = blockIdx.x;
    int bs = ((b & 7) << 5) + (b >> 3);
    int m0 = bs << 7;
    int g = bs >> 3;
    int tid = threadIdx.x;
    int lane = tid & 63;
    int wid = tid >> 6;
    int wr = (wid & 1) << 6, wc = (wid >> 1) << 6;
    int l16 = lane & 15, quad = lane >> 4;

    if (tid < 128) {
        int c = tid;
        double m = dsum1[c] / (double)Nn;
        double var = dsq1[c] / (double)Nn - m * m;
        float s = bn1g[c] * (float)(1.0 / sqrt(var + 1e-5));
        sc1[c] = s; sh1[c] = bn1b[c] - (float)m * s;
    }

    int ar = tid >> 2, ack = (tid & 3) * 8;
    int anode = m0 + ar;
    int aold = perm1[anode];
    float atv = tv1[anode];
    int abg = anode * SLAB, adg = deg[anode];
    int4 c0h = *(const int4*)&col[abg];
    int4 c1h = *(const int4*)&col[abg + 4];
    int anb[8] = {c0h.x, c0h.y, c0h.z, c0h.w, c1h.x, c1h.y, c1h.z, c1h.w};
    int aon[8]; float atn[8];
#pragma unroll
    for (int j = 0; j < 8; j++) {
        int nbv = (j < adg) ? anb[j] : anode;  // guard poison entries
        aon[j] = perm1[nbv];
        atn[j] = tv1[nbv];
    }
    __syncthreads();   // sc1/sh1 ready

    {   // A own row: all 4 k-slices, BN-relu-tanh transformed
#pragma unroll
        for (int kt = 0; kt < 4; kt++) {
            uint4 hv = *(const uint4*)&h1[((size_t)aold << 7) + kt * 32 + ack];
            float vals[8];
            unpk8(hv, vals);
#pragma unroll
            for (int q = 0; q < 8; q++) {
                int cc = kt * 32 + ack + q;
                vals[q] = fmaxf(vals[q] * sc1[cc] + sh1[cc], 0.f) * atv;
            }
            *(uint4*)&As[1][kt][ar][ack] = pack8(vals, 1.f);
        }
    }
    {   // A agg: all neighbor gathers (all k-slices) up front
        float aacc[4][8];
#pragma unroll
        for (int kt = 0; kt < 4; kt++)
#pragma unroll
            for (int q = 0; q < 8; q++) aacc[kt][q] = 0.f;
#pragma unroll
        for (int j = 0; j < 8; j++)
            if (j < adg) {
                const ushort* hp = &h1[(size_t)aon[j] << 7];
                float tn = atn[j];
#pragma unroll
                for (int kt = 0; kt < 4; kt++) {
                    uint4 u = *(const uint4*)&hp[kt * 32 + ack];
                    float f[8];
                    unpk8(u, f);
#pragma unroll
                    for (int q = 0; q < 8; q++) {
                        int cc = kt * 32 + ack + q;
                        aacc[kt][q] += fmaxf(f[q] * sc1[cc] + sh1[cc], 0.f) * tn;
                    }
                }
            }
        for (int i = abg + 8; i < abg + adg; i++) {
            int nbv = col[i];
            int on = perm1[nbv];
            float tn = tv1[nbv];
            const ushort* hp = &h1[(size_t)on << 7];
#pragma unroll
            for (int kt = 0; kt < 4; kt++) {
                uint4 u = *(const uint4*)&hp[kt * 32 + ack];
                float f[8];
                unpk8(u, f);
#pragma unroll
                for (int q = 0; q < 8; q++) {
                    int cc = kt * 32 + ack + q;
                    aacc[kt][q] += fmaxf(f[q] * sc1[cc] + sh1[cc], 0.f) * tn;
                }
            }
        }
        int cdg = adg < 1 ? 1 : adg;
        float inv = 1.f / (float)cdg;
#pragma unroll
        for (int kt = 0; kt < 4; kt++)
            *(uint4*)&As[0][kt][ar][ack] = pack8(aacc[kt], inv);
    }
    // B stage for k-step 0 into buffer 0
    for (int idx = tid; idx < 1024; idx += 512) {
        int rr = idx >> 2, ck = (idx & 3) * 8;
        *(uint4*)&Bs[0][0][rr][ck] = *(const uint4*)&Wtl[(size_t)rr * H1c + ck];
        *(uint4*)&Bs[0][1][rr][ck] = *(const uint4*)&Wtr[(size_t)rr * H1c + ck];
    }
    __syncthreads();

    f32x4 acc[4][4];
#pragma unroll
    for (int a = 0; a < 4; a++)
#pragma unroll
        for (int c = 0; c < 4; c++) acc[a][c] = (f32x4){0.f, 0.f, 0.f, 0.f};

#pragma unroll
    for (int kt = 0; kt < 4; kt++) {
        int bf = kt & 1;
        if (kt < 3) {   // prefetch next B into other buffer (overlaps MFMA)
            int kn = (kt + 1) * 32;
            for (int idx = tid; idx < 1024; idx += 512) {
                int rr = idx >> 2, ck = (idx & 3) * 8;
                *(uint4*)&Bs[bf ^ 1][0][rr][ck] =
                    *(const uint4*)&Wtl[(size_t)rr * H1c + kn + ck];
                *(uint4*)&Bs[bf ^ 1][1][rr][ck] =
                    *(const uint4*)&Wtr[(size_t)rr * H1c + kn + ck];
            }
        }
        short8 a[2][4], bfr[2][4];
#pragma unroll
        for (int s = 0; s < 2; s++)
#pragma unroll
            for (int mt = 0; mt < 4; mt++)
                a[s][mt] = *(const short8*)&As[s][kt][wr + mt * 16 + l16][quad * 8];
#pragma unroll
        for (int s = 0; s < 2; s++)
#pragma unroll
            for (int nt = 0; nt < 4; nt++)
                bfr[s][nt] = *(const short8*)&Bs[bf][s][wc + nt * 16 + l16][quad * 8];
#pragma unroll
        for (int mt = 0; mt < 4; mt++)
#pragma unroll
            for (int nt = 0; nt < 4; nt++) {
                acc[mt][nt] = __builtin_amdgcn_mfma_f32_16x16x32_bf16(
                    a[0][mt], bfr[0][nt], acc[mt][nt], 0, 0, 0);
                acc[mt][nt] = __builtin_amdgcn_mfma_f32_16x16x32_bf16(
                    a[1][mt], bfr[1][nt], acc[mt][nt], 0, 0, 0);
            }
        __syncthreads();
    }
    // P1: BN2 stats from acc+bias (no h2 write)
    {
        float s[4] = {0.f, 0.f, 0.f, 0.f}, sq[4] = {0.f, 0.f, 0.f, 0.f};
#pragma unroll
        for (int nt = 0; nt < 4; nt++) {
            int colx = wc + nt * 16 + l16;
            float bv = bias[colx];
#pragma unroll
            for (int mt = 0; mt < 4; mt++)
#pragma unroll
                for (int rr = 0; rr < 4; rr++) {
                    float ov = acc[mt][nt][rr] + bv;
                    s[nt] += ov; sq[nt] += ov * ov;
                }
        }
#pragma unroll
        for (int nt = 0; nt < 4; nt++) {
            float ss = s[nt], qq = sq[nt];
            ss += __shfl_down(ss, 16); qq += __shfl_down(qq, 16);
            ss += __shfl_down(ss, 32); qq += __shfl_down(qq, 32);
            if (quad == 0) {
                bsumS[wid & 1][wc + nt * 16 + l16] = ss;
                bsqS[wid & 1][wc + nt * 16 + l16] = qq;
            }
        }
        __syncthreads();
        if (tid < 256) {
            int c = tid;
            atomicAdd(&dsum[c], (double)(bsumS[0][c] + bsumS[1][c]));
            atomicAdd(&dsq[c], (double)(bsqS[0][c] + bsqS[1][c]));
        }
    }
    grid.sync();   // #1: stats complete

    // P2: score2 from registers
    if (tid < 256) {
        int c = tid;
        double m = dsum[c] / (double)N1c;
        double var = dsq[c] / (double)N1c - m * m;
        float s2 = bn2g[c] * (float)(1.0 / sqrt(var + 1e-5));
        sc2S[c] = s2;
        shfS[c] = (bn2b[c] - (float)m * s2) + bias[c] * s2;   // bias folded in
    }
    __syncthreads();
    float scc[4], shc[4];
#pragma unroll
    for (int nt = 0; nt < 4; nt++) {
        int c = wc + nt * 16 + l16;
        scc[nt] = sc2S[c]; shc[nt] = shfS[c];
    }
    float* basef = (float*)&Bs[0][0][0][0];
    float* rpS = basef;             // [4*128]
    float* rtS = basef + 512;       // [4*128]
    {
        float wlc[4], wtc[4];
#pragma unroll
        for (int nt = 0; nt < 4; nt++) {
            int c = wc + nt * 16 + l16;
            wlc[nt] = wrel[c]; wtc[nt] = wroot[c];
        }
#pragma unroll
        for (int mt = 0; mt < 4; mt++)
#pragma unroll
            for (int rr = 0; rr < 4; rr++) {
                float pr = 0.f, pt = 0.f;
#pragma unroll
                for (int nt = 0; nt < 4; nt++) {
                    float v = fmaxf(acc[mt][nt][rr] * scc[nt] + shc[nt], 0.f);
                    pr += v * wlc[nt]; pt += v * wtc[nt];
                }
#pragma unroll
                for (int off = 8; off; off >>= 1) {
                    pr += __shfl_down(pr, off);
                    pt += __shfl_down(pt, off);
                }
                if (l16 == 0) {
                    int rl = wr + mt * 16 + quad * 4 + rr;
                    rpS[(wid >> 1) * 128 + rl] = pr;
                    rtS[(wid >> 1) * 128 + rl] = pt;
                }
            }
        __syncthreads();
        if (tid < 128) {
            r2[m0 + tid] = rpS[tid] + rpS[128 + tid] + rpS[256 + tid] + rpS[384 + tid];
            root2[m0 + tid] = rtS[tid] + rtS[128 + tid] + rtS[256 + tid] + rtS[384 + tid];
        }
    }
    grid.sync();   // #2: r2/root2 complete

    // P3: per-graph radix select (32 blocks active) -> tvflag
    if ((bs & 7) == 0) {
        float* rLS    = basef + 1920;    // [1024]
        float* svalsS = basef + 2944;    // [1024]
        uint*  histS  = (uint*)(basef + 3968);  // [257]
        uint*  wsumS  = histS + 257;     // [8]
        uint*  sbS    = wsumS + 8;
        uint*  sremS  = sbS + 1;
        int base = g * K1c;
        rLS[tid] = r2[base + tid];
        rLS[tid + 512] = r2[base + tid + 512];
        if (tid < 257) histS[tid] = 0;
        __syncthreads();
        float bv2 = brel[0];
#pragma unroll
        for (int j = 0; j < 2; j++) {
            int i = tid + (j << 9);
            int node = base + i;
            float a2 = bv2 + root2[node];
            int e0 = node * SLAB, dg = deg[node];
            int4 cc0 = *(const int4*)&col[e0];
            int4 cc1 = *(const int4*)&col[e0 + 4];
            int nb[8] = {cc0.x, cc0.y, cc0.z, cc0.w, cc1.x, cc1.y, cc1.z, cc1.w};
#pragma unroll
            for (int q = 0; q < 8; q++)
                if (q < dg) a2 += rLS[nb[q] - base];
            for (int e = e0 + 8; e < e0 + dg; e++) a2 += rLS[col[e] - base];
            svalsS[i] = a2;
        }
        __syncthreads();
        uint prefix = 0, himask = 0, rem = (uint)K2c;
        for (int shift = 24; shift >= 0; shift -= 8) {
#pragma unroll
            for (int j = 0; j < 2; j++) {
                uint kk = fkey(svalsS[tid + (j << 9)]);
                if ((kk & himask) == prefix) atomicAdd(&histS[(kk >> shift) & 255], 1);
            }
            __syncthreads();
            if (tid < 64) {
                int L = tid;
                uint h0 = histS[4 * L], hh1 = histS[4 * L + 1], hh2 = histS[4 * L + 2],
                     h3 = histS[4 * L + 3];
                uint s3 = h3, s2v = hh2 + s3, s1 = hh1 + s2v, s0 = h0 + s1;
                uint v = s0;
                for (int off = 1; off < 64; off <<= 1) {
                    uint u = __shfl_down(v, off);
                    if (L + off < 64) v += u;
                }
                uint above = v - s0;
                histS[4 * L] = s0 + above;
                histS[4 * L + 1] = s1 + above;
                histS[4 * L + 2] = s2v + above;
                histS[4 * L + 3] = s3 + above;
            }
            __syncthreads();
            if (tid < 256) {
                uint sb = histS[tid], sb1 = histS[tid + 1];
                if (sb >= rem && sb1 < rem) { *sbS = (uint)tid; *sremS = rem - sb1; }
            }
            __syncthreads();
            prefix |= (*sbS << shift);
            rem = *sremS;
            himask |= (0xFFu << shift);
            if (tid < 256) histS[tid] = 0;
            __syncthreads();
        }
        uint thr = prefix, tieM = rem;
        uint gcnt = 0, ecnt = 0, gflags = 0, eflags = 0;
#pragma unroll
        for (int j = 0; j < 2; j++) {
            uint kk = fkey(svalsS[tid + (j << 9)]);
            if (kk > thr) { gflags |= 1u << j; gcnt++; }
            else if (kk == thr) { eflags |= 1u << j; ecnt++; }
        }
        uint key = (gcnt << 16) | ecnt;
        uint v = key;
        for (int off = 1; off < 64; off <<= 1) {
            uint u = __shfl_up(v, off);
            if (lane >= off) v += u;
        }
        if (lane == 63) wsumS[wid] = v;
        __syncthreads();
        if (tid < 8) {
            uint w0 = wsumS[tid], w = w0;
            for (int off = 1; off < 8; off <<= 1) {
                uint u = __shfl_up(w, off);
                if ((int)tid >= off) w += u;
            }
            wsumS[tid] = w - w0;
        }
        __syncthreads();
        uint excl = (v - key) + wsumS[wid];
        uint gbase = excl >> 16, ebase = excl & 0xFFFFu;
#pragma unroll
        for (int j = 0; j < 2; j++) {
            bool gt = (gflags >> j) & 1u;
            bool eq = (eflags >> j) & 1u;
            int i = tid + (j << 9);
            bool selv = gt || (eq && ebase < tieM);
            tvflag[base + i] = selv ? tanhf(svalsS[i]) : 0.f;
            gbase += gt ? 1u : 0u;
            ebase += eq ? 1u : 0u;
        }
    }
    grid.sync();   // #3: tvflag complete

    // P4: pool from registers
    {
        float* flagS = basef + 1024;   // [128]
        float* poolS = basef + 1152;   // [256]
        if (tid < 128) flagS[tid] = tvflag[m0 + tid];
        if (tid < 256) poolS[tid] = 0.f;
        __syncthreads();
        float pc[4] = {0.f, 0.f, 0.f, 0.f};
#pragma unroll
        for (int mt = 0; mt < 4; mt++)
#pragma unroll
            for (int rr = 0; rr < 4; rr++) {
                int rl = wr + mt * 16 + quad * 4 + rr;
                float fl = flagS[rl];
#pragma unroll
                for (int nt = 0; nt < 4; nt++)
                    pc[nt] += fmaxf(acc[mt][nt][rr] * scc[nt] + shc[nt], 0.f) * fl;
            }
#pragma unroll
        for (int nt = 0; nt < 4; nt++) {
            pc[nt] += __shfl_down(pc[nt], 16);
            pc[nt] += __shfl_down(pc[nt], 32);
        }
        if (quad == 0) {
#pragma unroll
            for (int nt = 0; nt < 4; nt++)
                atomicAdd(&poolS[wc + nt * 16 + l16], pc[nt]);
        }
        __syncthreads();
        if (tid < 256) atomicAdd(&pooled[g * H2c + tid], poolS[tid]);
    }
    grid.sync();   // #4: pooled complete

    // P5: readout (32 blocks active)
    if ((bs & 7) == 0) {
        float* redS = basef + 1408;    // [512]
        if (tid < 256) {
            float s = fmaxf(pooled[g * H2c + tid] * (1.f / (float)K2c), 0.f);
            redS[tid] = s * Wlin[2 * tid];
            redS[256 + tid] = s * Wlin[2 * tid + 1];
        }
        __syncthreads();
        for (int off = 128; off; off >>= 1) {
            if (tid < off) {
                redS[tid] += redS[tid + off];
                redS[256 + tid] += redS[256 + tid + off];
            }
            __syncthreads();
        }
        if (tid == 0) {
            float o0 = redS[0] + blin[0], o1 = redS[256] + blin[1];
            float mm = fmaxf(o0, o1);
            float e0 = expf(o0 - mm), e1 = expf(o1 - mm);
            float inv = 1.f / (e0 + e1);
            out[g * 2 + 0] = e0 * inv;
            out[g * 2 + 1] = e1 * inv;
        }
    }
}

extern "C" void kernel_launch(void* const* d_in, const int* in_sizes, int n_in,
                              void* d_out, int out_size, void* d_ws, size_t ws_size,
                              hipStream_t stream) {
    const float* x      = (const float*)d_in[0];
    const int*   ei     = (const int*)d_in[1];
    const int*   src    = ei;
    const int*   tgt    = ei + Ee;
    const float* W1l    = (const float*)d_in[3];
    const float* b1l    = (const float*)d_in[4];
    const float* W1r    = (const float*)d_in[5];
    const float* bn1g   = (const float*)d_in[6];
    const float* bn1b   = (const float*)d_in[7];
    const float* p1Wrel = (const float*)d_in[8];
    const float* p1brel = (const float*)d_in[9];
    const float* p1Wroot= (const float*)d_in[10];
    const float* W2l    = (const float*)d_in[11];
    const float* b2l    = (const float*)d_in[12];
    const float* W2r    = (const float*)d_in[13];
    const float* bn2g   = (const float*)d_in[14];
    const float* bn2b   = (const float*)d_in[15];
    const float* p2Wrel = (const float*)d_in[16];
    const float* p2brel = (const float*)d_in[17];
    const float* p2Wroot= (const float*)d_in[18];
    const float* Wlin   = (const float*)d_in[19];
    const float* blin   = (const float*)d_in[20];
    float* out = (float*)d_out;
    char* ws = (char*)d_ws;

    size_t o = 0;
    auto A = [&](size_t b) { size_t r = o; o += (b + 255) & ~(size_t)255; return r; };
    size_t oH1   = A((size_t)Nn * H1c * 2);        // h1 bf16 (live through gemm2s)
    size_t oCol1 = A((size_t)Nn * SLAB * 4);
    size_t oCol2 = A((size_t)N1c * SLAB * 4);
    size_t oWc1  = A((size_t)Nn * 4);
    size_t oR1   = A((size_t)Nn * 4);
    size_t oRoot1= A((size_t)Nn * 4);
    size_t oPerm1= A((size_t)N1c * 4);
    size_t oTv1  = A((size_t)N1c * 4);
    size_t oWc2  = A((size_t)N1c * 4);
    size_t oR2   = A((size_t)N1c * 4);
    size_t oRoot2= A((size_t)N1c * 4);
    size_t oFlag = A((size_t)N1c * 4);
    size_t oDst  = A(768 * 8);
    size_t oWt1l = A(8192 * 2);
    size_t oWt1r = A(8192 * 2);
    size_t oWt2l = A(32768 * 2);
    size_t oWt2r = A(32768 * 2);
    size_t oPool = A(Bg * H2c * 4);
    (void)ws_size; (void)in_sizes; (void)n_in; (void)out_size;

    ushort* h1   = (ushort*)(ws + oH1);
    int* col1    = (int*)(ws + oCol1);
    int* col2    = (int*)(ws + oCol2);
    int* wc1     = (int*)(ws + oWc1);
    float* r1    = (float*)(ws + oR1);
    float* root1 = (float*)(ws + oRoot1);
    int* perm1   = (int*)(ws + oPerm1);
    float* tv1   = (float*)(ws + oTv1);
    int* wc2     = (int*)(ws + oWc2);
    float* r2    = (float*)(ws + oR2);
    float* root2 = (float*)(ws + oRoot2);
    float* tvflag= (float*)(ws + oFlag);
    double* dsum1= (double*)(ws + oDst);
    double* dsq1 = dsum1 + 128;
    double* dsum2= dsum1 + 256;
    double* dsq2 = dsum1 + 512;
    ushort* T1l  = (ushort*)(ws + oWt1l);
    ushort* T1r  = (ushort*)(ws + oWt1r);
    ushort* T2l  = (ushort*)(ws + oWt2l);
    ushort* T2r  = (ushort*)(ws + oWt2r);
    float* pooled= (float*)(ws + oPool);

    // 1. init zeros (wc1, BN stats, pooled)
    init_kernel<<<(INIT_TOTAL + 255) / 256, 256, 0, stream>>>(
        (int4*)wc1, (int4*)dsum1, (int4*)pooled);

    // 2. fused: fill1 || weight transposes
    prep2_kernel<<<PREP2_TOTAL / 256, 256, 0, stream>>>(
        src, tgt, W1l, W1r, W2l, W2r, T1l, T1r, T2l, T2r, wc1, col1);

    // 3. fused agg1 + GEMM1 from f32 x (+ BN1 stats)
    gemm1f_kernel<<<512, 512, 0, stream>>>(x, wc1, col1, T1l, T1r, b1l, h1,
                                           dsum1, dsq1);

    // 4. score1 full-grid (r1/root1)
    score_kernel<H1c><<<Nn / 32, 256, 0, stream>>>(h1, dsum1, dsq1, bn1g, bn1b, p1Wrel,
                                                   p1Wroot, r1, root1, Nn);

    // 5. svals + radix select + fused layer2 CSR build
    sel1_kernel<<<Bg, 1024, 0, stream>>>(r1, root1, wc1, col1, p1brel, perm1, tv1,
                                         wc2, col2);

    // 6. cooperative mega: GEMM2 + stats + score2 + select + pool + readout
    {
        void* kargs[] = {
            (void*)&h1, (void*)&perm1, (void*)&tv1,
            (void*)&dsum1, (void*)&dsq1, (void*)&bn1g, (void*)&bn1b,
            (void*)&wc2, (void*)&col2,
            (void*)&T2l, (void*)&T2r, (void*)&b2l,
            (void*)&dsum2, (void*)&dsq2,
            (void*)&bn2g, (void*)&bn2b,
            (void*)&p2Wrel, (void*)&p2Wroot, (void*)&p2brel,
            (void*)&r2, (void*)&root2, (void*)&tvflag, (void*)&pooled,
            (void*)&Wlin, (void*)&blin, (void*)&out
        };
        hipLaunchCooperativeKernel((const void*)gemm2s_kernel, dim3(256), dim3(512),
                                   kargs, 0, stream);
    }
}

// Round 11
// 217.630 us; speedup vs baseline: 1.5951x; 1.5951x over previous
//
#include <hip/hip_runtime.h>
#include <math.h>

#define Bg   32
#define NPGc 2048
#define Nn   (Bg*NPGc)      // 65536
#define DEGc 8
#define Ee   (Nn*DEGc)      // 524288
#define INc  64
#define H1c  128
#define H2c  256
#define K1c  1024
#define K2c  512
#define N1c  (Bg*K1c)       // 32768
#define N2c  (Bg*K2c)       // 16384
#define SLAB 64             // fixed CSR slab per node

typedef __attribute__((ext_vector_type(8))) short short8;
typedef __attribute__((ext_vector_type(4))) float f32x4;

__device__ __forceinline__ ushort f2bf(float f) {
    uint u = __float_as_uint(f);
    uint r = (u + 0x7fffu + ((u >> 16) & 1u)) >> 16;
    return (ushort)r;
}
__device__ __forceinline__ float bf2f(ushort v) { return __uint_as_float((uint)v << 16); }
__device__ __forceinline__ float bfhi(uint v) { return __uint_as_float(v & 0xffff0000u); }
__device__ __forceinline__ float bflo(uint v) { return __uint_as_float(v << 16); }
__device__ __forceinline__ uint fkey(float f) {
    uint u = __float_as_uint(f);
    return u ^ ((uint)((int)u >> 31) | 0x80000000u);
}
__device__ __forceinline__ void unpk8(uint4 v, float* f) {
    f[0] = bflo(v.x); f[1] = bfhi(v.x);
    f[2] = bflo(v.y); f[3] = bfhi(v.y);
    f[4] = bflo(v.z); f[5] = bfhi(v.z);
    f[6] = bflo(v.w); f[7] = bfhi(v.w);
}
__device__ __forceinline__ uint4 pack8(const float* a, float inv) {
    uint4 o;
    o.x = (uint)f2bf(a[0] * inv) | ((uint)f2bf(a[1] * inv) << 16);
    o.y = (uint)f2bf(a[2] * inv) | ((uint)f2bf(a[3] * inv) << 16);
    o.z = (uint)f2bf(a[4] * inv) | ((uint)f2bf(a[5] * inv) << 16);
    o.w = (uint)f2bf(a[6] * inv) | ((uint)f2bf(a[7] * inv) << 16);
    return o;
}
__device__ __forceinline__ void accf8(float* a, const float* p) {
    float4 u0 = *(const float4*)p;
    float4 u1 = *(const float4*)(p + 4);
    a[0] += u0.x; a[1] += u0.y; a[2] += u0.z; a[3] += u0.w;
    a[4] += u1.x; a[5] += u1.y; a[6] += u1.z; a[7] += u1.w;
}

// ---------------- init: zero wc1/stats ----------------
__global__ void init_kernel(int4* __restrict__ wc1, int4* __restrict__ dstats) {
    int id = blockIdx.x * blockDim.x + threadIdx.x;
    int4 z = {0, 0, 0, 0};
    if (id < 16384) { wc1[id] = z; return; }
    id -= 16384;
    if (id < 384)   { dstats[id] = z; }
}
#define INIT_TOTAL (16384 + 384)

// ------- prep2: fill1 (slab CSR) || weight transposes, grid-partitioned -------
__global__ void prep2_kernel(const int* __restrict__ src, const int* __restrict__ tgt,
                             const float* __restrict__ W1l, const float* __restrict__ W1r,
                             const float* __restrict__ W2l, const float* __restrict__ W2r,
                             ushort* __restrict__ T1l, ushort* __restrict__ T1r,
                             ushort* __restrict__ T2l, ushort* __restrict__ T2r,
                             int* __restrict__ wc1, int* __restrict__ col1) {
    int id = blockIdx.x * blockDim.x + threadIdx.x;
    if (id < Ee) {
        int t = tgt[id];
        int p = atomicAdd(&wc1[t], 1);
        col1[t * SLAB + p] = src[id];
        return;
    }
    id -= Ee;
    if (id < 8192) {
        int c = id / 64, k = id % 64;
        T1l[id] = f2bf(W1l[k * 128 + c]);
        T1r[id] = f2bf(W1r[k * 128 + c]);
        return;
    }
    id -= 8192;
    if (id < 32768) {
        int c = id / 128, k = id % 128;
        T2l[id] = f2bf(W2l[k * 256 + c]);
        T2r[id] = f2bf(W2r[k * 256 + c]);
    }
}
#define PREP2_TOTAL (Ee + 8192 + 32768)

// ---- gemm1f: fused agg1 + SAGEConv1 GEMM from f32 x, full-K staged, 1 barrier ----
__global__ __launch_bounds__(512) void gemm1f_kernel(
        const float* __restrict__ x, const int* __restrict__ deg,
        const int* __restrict__ col, const ushort* __restrict__ Wtl,
        const ushort* __restrict__ Wtr, const float* __restrict__ bias,
        ushort* __restrict__ out, double* __restrict__ dsum,
        double* __restrict__ dsq) {
    __shared__ ushort As[2][2][128][36];   // [src][kt][row][ch]
    __shared__ ushort Bs[2][2][128][36];   // full B
    __shared__ float bsumS[2][128], bsqS[2][128];
    int b = blockIdx.x;
    int bs = ((b & 7) << 6) + (b >> 3);    // graph g -> XCD g/4
    int m0 = bs << 7;
    int lane = threadIdx.x & 63;
    int wid = threadIdx.x >> 6;
    int wr = (wid & 1) << 6, wc = (wid >> 1) << 5;
    int l16 = lane & 15, quad = lane >> 4;

    int ar = threadIdx.x >> 2, ack = (threadIdx.x & 3) * 8;
    int anode = m0 + ar;
    int abg = anode * SLAB, adg = deg[anode];
    int4 c0h = *(const int4*)&col[abg];
    int4 c1h = *(const int4*)&col[abg + 4];
    int anb[8] = {c0h.x, c0h.y, c0h.z, c0h.w, c1h.x, c1h.y, c1h.z, c1h.w};

    {   // B full stage
        int r = threadIdx.x >> 2, ck = (threadIdx.x & 3) * 8;
#pragma unroll
        for (int kt = 0; kt < 2; kt++) {
            *(uint4*)&Bs[0][kt][r][ck] = *(const uint4*)&Wtl[(size_t)r * INc + kt * 32 + ck];
            *(uint4*)&Bs[1][kt][r][ck] = *(const uint4*)&Wtr[(size_t)r * INc + kt * 32 + ck];
        }
    }
    {   // A own row (f32 -> bf16), both k-slices
#pragma unroll
        for (int kt = 0; kt < 2; kt++) {
            const float* xp = &x[(size_t)anode * INc + kt * 32 + ack];
            float vals[8];
            float4 v0 = *(const float4*)xp, v1 = *(const float4*)(xp + 4);
            vals[0] = v0.x; vals[1] = v0.y; vals[2] = v0.z; vals[3] = v0.w;
            vals[4] = v1.x; vals[5] = v1.y; vals[6] = v1.z; vals[7] = v1.w;
            *(uint4*)&As[1][kt][ar][ack] = pack8(vals, 1.f);
        }
    }
    {   // A agg: all neighbor gathers up front, both k-slices
        float aacc[2][8];
#pragma unroll
        for (int kt = 0; kt < 2; kt++)
#pragma unroll
            for (int q = 0; q < 8; q++) aacc[kt][q] = 0.f;
#pragma unroll
        for (int j = 0; j < 8; j++)
            if (j < adg) {
                const float* xp = &x[(size_t)anb[j] * INc + ack];
#pragma unroll
                for (int kt = 0; kt < 2; kt++) accf8(aacc[kt], xp + kt * 32);
            }
        for (int i = abg + 8; i < abg + adg; i++) {
            const float* xp = &x[(size_t)col[i] * INc + ack];
#pragma unroll
            for (int kt = 0; kt < 2; kt++) accf8(aacc[kt], xp + kt * 32);
        }
        int cdg = adg < 1 ? 1 : adg;
        float inv = 1.f / (float)cdg;
#pragma unroll
        for (int kt = 0; kt < 2; kt++)
            *(uint4*)&As[0][kt][ar][ack] = pack8(aacc[kt], inv);
    }
    __syncthreads();

    f32x4 acc[4][2];
#pragma unroll
    for (int a = 0; a < 4; a++)
#pragma unroll
        for (int c = 0; c < 2; c++) acc[a][c] = (f32x4){0.f, 0.f, 0.f, 0.f};

#pragma unroll
    for (int kt = 0; kt < 2; kt++) {
        short8 a[2][4], bfr[2][2];
#pragma unroll
        for (int s = 0; s < 2; s++)
#pragma unroll
            for (int mt = 0; mt < 4; mt++)
                a[s][mt] = *(const short8*)&As[s][kt][wr + mt * 16 + l16][quad * 8];
#pragma unroll
        for (int s = 0; s < 2; s++)
#pragma unroll
            for (int nt = 0; nt < 2; nt++)
                bfr[s][nt] = *(const short8*)&Bs[s][kt][wc + nt * 16 + l16][quad * 8];
#pragma unroll
        for (int mt = 0; mt < 4; mt++)
#pragma unroll
            for (int nt = 0; nt < 2; nt++) {
                acc[mt][nt] = __builtin_amdgcn_mfma_f32_16x16x32_bf16(
                    a[0][mt], bfr[0][nt], acc[mt][nt], 0, 0, 0);
                acc[mt][nt] = __builtin_amdgcn_mfma_f32_16x16x32_bf16(
                    a[1][mt], bfr[1][nt], acc[mt][nt], 0, 0, 0);
            }
    }
    float s[2] = {0.f, 0.f}, sq[2] = {0.f, 0.f};
#pragma unroll
    for (int nt = 0; nt < 2; nt++) {
        int colx = wc + nt * 16 + l16;
        float bv = bias[colx];
#pragma unroll
        for (int mt = 0; mt < 4; mt++)
#pragma unroll
            for (int rr = 0; rr < 4; rr++) {
                int row = m0 + wr + mt * 16 + quad * 4 + rr;
                float ov = acc[mt][nt][rr] + bv;
                out[(size_t)row * H1c + colx] = f2bf(ov);
                s[nt] += ov; sq[nt] += ov * ov;
            }
    }
#pragma unroll
    for (int nt = 0; nt < 2; nt++) {
        float ss = s[nt], qq = sq[nt];
        ss += __shfl_down(ss, 16); qq += __shfl_down(qq, 16);
        ss += __shfl_down(ss, 32); qq += __shfl_down(qq, 32);
        if (quad == 0) {
            bsumS[wid & 1][wc + nt * 16 + l16] = ss;
            bsqS[wid & 1][wc + nt * 16 + l16] = qq;
        }
    }
    __syncthreads();
    if (threadIdx.x < 128) {
        int c = threadIdx.x;
        atomicAdd(&dsum[c], (double)(bsumS[0][c] + bsumS[1][c]));
        atomicAdd(&dsq[c], (double)(bsqS[0][c] + bsqS[1][c]));
    }
}

// ------- score: full-grid, 8 lanes/node, XCD-affine block swizzle -------
// blocks-per-graph = npg/32; swizzle puts graph g's blocks on XCD g/4 (matches gemm).
template<int C>
__global__ __launch_bounds__(256) void score_kernel(const ushort* __restrict__ h,
                                                    const double* __restrict__ dsum,
                                                    const double* __restrict__ dsq,
                                                    const float* __restrict__ g,
                                                    const float* __restrict__ b,
                                                    const float* __restrict__ wrel,
                                                    const float* __restrict__ wroot,
                                                    float* __restrict__ r,
                                                    float* __restrict__ root,
                                                    int n, int npg) {
    __shared__ float sc[C], sh[C], wrl[C], wrt[C];
    if ((int)threadIdx.x < C) {
        int c = threadIdx.x;
        double m = dsum[c] / (double)n;
        double var = dsq[c] / (double)n - m * m;
        float s = g[c] * (float)(1.0 / sqrt(var + 1e-5));
        sc[c] = s; sh[c] = b[c] - (float)m * s;
        wrl[c] = wrel[c]; wrt[c] = wroot[c];
    }
    __syncthreads();
    int bid = blockIdx.x;
    int xcd = bid & 7, t = bid >> 3;
    int gg = xcd * 4 + (t & 3);        // graph -> XCD graph/4
    int j = t >> 2;                    // block within graph
    int node = gg * npg + j * 32 + ((int)threadIdx.x >> 3);
    int ln = threadIdx.x & 7;
    float rr = 0.f, rt = 0.f;
#pragma unroll
    for (int p = 0; p < C / 64; p++) {
        int cb = p * 64 + ln * 8;
        uint4 v = *(const uint4*)&h[(size_t)node * C + cb];
        float vv[8];
        unpk8(v, vv);
#pragma unroll
        for (int q = 0; q < 8; q++) {
            int cc = cb + q;
            float val = fmaxf(vv[q] * sc[cc] + sh[cc], 0.f);
            rr += val * wrl[cc];
            rt += val * wrt[cc];
        }
    }
#pragma unroll
    for (int off = 4; off; off >>= 1) {
        rr += __shfl_down(rr, off);
        rt += __shfl_down(rt, off);
    }
    if (ln == 0) { r[node] = rr; root[node] = rt; }
}

// ---- sel1: LDS r-slice + svals + radix select + perm/tv/map (XCD-affine graph) ----
__global__ void __launch_bounds__(1024) sel1_kernel(const float* __restrict__ r,
                                                    const float* __restrict__ root,
                                                    const int* __restrict__ deg,
                                                    const int* __restrict__ col,
                                                    const float* __restrict__ brel,
                                                    int* __restrict__ perm,
                                                    float* __restrict__ tval,
                                                    int* __restrict__ map) {
    __shared__ float rL[2048];
    __shared__ float svals[2048];
    __shared__ uint hist[257];
    __shared__ uint wsum[16];
    __shared__ uint s_b, s_rem;
    int g = ((blockIdx.x & 7) << 2) + (blockIdx.x >> 3);   // graph g -> XCD g/4
    int tid = threadIdx.x;
    int lane = tid & 63, wid = tid >> 6;
    int base = g * NPGc;
    rL[tid] = r[base + tid];
    rL[tid + 1024] = r[base + tid + 1024];
    if (tid < 257) hist[tid] = 0;
    __syncthreads();
    float bv = brel[0];
#pragma unroll
    for (int j = 0; j < 2; j++) {
        int i = tid + (j << 10);
        int node = base + i;
        float acc = bv + root[node];
        int e0 = node * SLAB, dg = deg[node];
        int4 c0 = *(const int4*)&col[e0];
        int4 c1 = *(const int4*)&col[e0 + 4];
        int nb[8] = {c0.x, c0.y, c0.z, c0.w, c1.x, c1.y, c1.z, c1.w};
#pragma unroll
        for (int q = 0; q < 8; q++)
            if (q < dg) acc += rL[nb[q] - base];
        for (int e = e0 + 8; e < e0 + dg; e++) acc += rL[col[e] - base];
        svals[i] = acc;
    }
    __syncthreads();

    uint prefix = 0, himask = 0, rem = (uint)K1c;
    for (int shift = 24; shift >= 0; shift -= 8) {
#pragma unroll
        for (int j = 0; j < 2; j++) {
            uint kk = fkey(svals[tid + (j << 10)]);
            if ((kk & himask) == prefix) atomicAdd(&hist[(kk >> shift) & 255], 1);
        }
        __syncthreads();
        if (tid < 64) {
            int L = tid;
            uint h0 = hist[4 * L], h1v = hist[4 * L + 1], h2v = hist[4 * L + 2],
                 h3 = hist[4 * L + 3];
            uint s3 = h3, s2 = h2v + s3, s1 = h1v + s2, s0 = h0 + s1;
            uint v = s0;
            for (int off = 1; off < 64; off <<= 1) {
                uint u = __shfl_down(v, off);
                if (L + off < 64) v += u;
            }
            uint above = v - s0;
            hist[4 * L] = s0 + above;
            hist[4 * L + 1] = s1 + above;
            hist[4 * L + 2] = s2 + above;
            hist[4 * L + 3] = s3 + above;
        }
        __syncthreads();
        if (tid < 256) {
            uint sb = hist[tid], sb1 = hist[tid + 1];
            if (sb >= rem && sb1 < rem) { s_b = (uint)tid; s_rem = rem - sb1; }
        }
        __syncthreads();
        prefix |= (s_b << shift);
        rem = s_rem;
        himask |= (0xFFu << shift);
        if (tid < 256) hist[tid] = 0;
        __syncthreads();
    }
    uint thr = prefix;
    uint tieM = rem;
    uint gcnt = 0, ecnt = 0, gflags = 0, eflags = 0;
#pragma unroll
    for (int j = 0; j < 2; j++) {
        uint kk = fkey(svals[tid + (j << 10)]);
        if (kk > thr) { gflags |= 1u << j; gcnt++; }
        else if (kk == thr) { eflags |= 1u << j; ecnt++; }
    }
    uint key = (gcnt << 16) | ecnt;
    uint v = key;
    for (int off = 1; off < 64; off <<= 1) {
        uint u = __shfl_up(v, off);
        if (lane >= off) v += u;
    }
    if (lane == 63) wsum[wid] = v;
    __syncthreads();
    if (tid < 16) {
        uint w0 = wsum[tid], w = w0;
        for (int off = 1; off < 16; off <<= 1) {
            uint u = __shfl_up(w, off);
            if ((int)tid >= off) w += u;
        }
        wsum[tid] = w - w0;
    }
    __syncthreads();
    uint excl = (v - key) + wsum[wid];
    uint gbase = excl >> 16, ebase = excl & 0xFFFFu;
#pragma unroll
    for (int j = 0; j < 2; j++) {
        bool gt = (gflags >> j) & 1u;
        bool eq = (eflags >> j) & 1u;
        int i = tid + (j << 10);
        int o = -1;
        if (gt || (eq && ebase < tieM)) {
            uint pos = gbase + min(ebase, tieM);
            o = g * K1c + (int)pos;
            perm[o] = base + i;
            tval[o] = tanhf(svals[i]);
        }
        map[base + i] = o;
        gbase += gt ? 1u : 0u;
        ebase += eq ? 1u : 0u;
    }
}

// ---- nofill2: node-parallel layer2 slab derivation (no atomics, no src/tgt read) ----
__global__ void __launch_bounds__(256) nofill2_kernel(
        const int* __restrict__ perm1, const int* __restrict__ map1,
        const int* __restrict__ deg1, const int* __restrict__ col1,
        int* __restrict__ wc2, int* __restrict__ col2) {
    int n = blockIdx.x * 256 + threadIdx.x;   // new id
    int o = perm1[n];                         // old id
    int e0 = o * SLAB, dg = deg1[o];
    int4 c0 = *(const int4*)&col1[e0];
    int4 c1 = *(const int4*)&col1[e0 + 4];
    int nb[8] = {c0.x, c0.y, c0.z, c0.w, c1.x, c1.y, c1.z, c1.w};
    int cnt = 0;
    int ob = n * SLAB;
#pragma unroll
    for (int j = 0; j < 8; j++) {
        if (j < dg) {
            int m = map1[nb[j]];
            if (m >= 0) col2[ob + cnt++] = m;
        }
    }
    for (int e = e0 + 8; e < e0 + dg; e++) {
        int m = map1[col1[e]];
        if (m >= 0) col2[ob + cnt++] = m;
    }
    wc2[n] = cnt;
}

// ---- gemm2f: fused BN1-apply/tanh + agg2 + SAGEConv2 GEMM, full-K A staged ----
__global__ __launch_bounds__(512) void gemm2f_kernel(
        const ushort* __restrict__ h1, const int* __restrict__ perm1,
        const float* __restrict__ tv1, const double* __restrict__ dsum1,
        const double* __restrict__ dsq1, const float* __restrict__ bn1g,
        const float* __restrict__ bn1b, const int* __restrict__ deg,
        const int* __restrict__ col, const ushort* __restrict__ Wtl,
        const ushort* __restrict__ Wtr, const float* __restrict__ bias,
        ushort* __restrict__ out, double* __restrict__ dsum,
        double* __restrict__ dsq) {
    __shared__ ushort As[2][4][128][36];       // [src][kt][row][ch]  73.7 KB
    __shared__ ushort Bs[2][2][256][36];       // [buf][src][row][ch] 73.7 KB
    __shared__ float bsumS[2][256], bsqS[2][256];
    __shared__ float sc1[128], sh1[128];
    int b = blockIdx.x;
    int bs = ((b & 7) << 5) + (b >> 3);        // graph g -> XCD g/4
    int m0 = bs << 7;
    int lane = threadIdx.x & 63;
    int wid = threadIdx.x >> 6;
    int wr = (wid & 1) << 6, wc = (wid >> 1) << 6;
    int l16 = lane & 15, quad = lane >> 4;

    if (threadIdx.x < 128) {
        int c = threadIdx.x;
        double m = dsum1[c] / (double)Nn;
        double var = dsq1[c] / (double)Nn - m * m;
        float s = bn1g[c] * (float)(1.0 / sqrt(var + 1e-5));
        sc1[c] = s; sh1[c] = bn1b[c] - (float)m * s;
    }

    // hoisted per-thread A-staging indices (col2: new-id CSR)
    int ar = threadIdx.x >> 2, ack = (threadIdx.x & 3) * 8;
    int anode = m0 + ar;
    int aold = perm1[anode];
    float atv = tv1[anode];
    int abg = anode * SLAB, adg = deg[anode];
    int4 c0h = *(const int4*)&col[abg];
    int4 c1h = *(const int4*)&col[abg + 4];
    int anb[8] = {c0h.x, c0h.y, c0h.z, c0h.w, c1h.x, c1h.y, c1h.z, c1h.w};
    int aon[8]; float atn[8];
#pragma unroll
    for (int j = 0; j < 8; j++) {
        int nbv = (j < adg) ? anb[j] : anode;  // guard poison entries
        aon[j] = perm1[nbv];
        atn[j] = tv1[nbv];
    }
    __syncthreads();   // sc1/sh1 ready

    {   // A own row: all 4 k-slices, BN-relu-tanh transformed
#pragma unroll
        for (int kt = 0; kt < 4; kt++) {
            uint4 hv = *(const uint4*)&h1[((size_t)aold << 7) + kt * 32 + ack];
            float vals[8];
            unpk8(hv, vals);
#pragma unroll
            for (int q = 0; q < 8; q++) {
                int cc = kt * 32 + ack + q;
                vals[q] = fmaxf(vals[q] * sc1[cc] + sh1[cc], 0.f) * atv;
            }
            *(uint4*)&As[1][kt][ar][ack] = pack8(vals, 1.f);
        }
    }
    {   // A agg: all neighbor gathers (all k-slices) up front
        float aacc[4][8];
#pragma unroll
        for (int kt = 0; kt < 4; kt++)
#pragma unroll
            for (int q = 0; q < 8; q++) aacc[kt][q] = 0.f;
#pragma unroll
        for (int j = 0; j < 8; j++)
            if (j < adg) {
                const ushort* hp = &h1[(size_t)aon[j] << 7];
                float tn = atn[j];
#pragma unroll
                for (int kt = 0; kt < 4; kt++) {
                    uint4 u = *(const uint4*)&hp[kt * 32 + ack];
                    float f[8];
                    unpk8(u, f);
#pragma unroll
                    for (int q = 0; q < 8; q++) {
                        int cc = kt * 32 + ack + q;
                        aacc[kt][q] += fmaxf(f[q] * sc1[cc] + sh1[cc], 0.f) * tn;
                    }
                }
            }
        for (int i = abg + 8; i < abg + adg; i++) {
            int nbv = col[i];
            int on = perm1[nbv];
            float tn = tv1[nbv];
            const ushort* hp = &h1[(size_t)on << 7];
#pragma unroll
            for (int kt = 0; kt < 4; kt++) {
                uint4 u = *(const uint4*)&hp[kt * 32 + ack];
                float f[8];
                unpk8(u, f);
#pragma unroll
                for (int q = 0; q < 8; q++) {
                    int cc = kt * 32 + ack + q;
                    aacc[kt][q] += fmaxf(f[q] * sc1[cc] + sh1[cc], 0.f) * tn;
                }
            }
        }
        int cdg = adg < 1 ? 1 : adg;
        float inv = 1.f / (float)cdg;
#pragma unroll
        for (int kt = 0; kt < 4; kt++)
            *(uint4*)&As[0][kt][ar][ack] = pack8(aacc[kt], inv);
    }
    // B stage for k-step 0 into buffer 0
    for (int idx = threadIdx.x; idx < 1024; idx += 512) {
        int rr = idx >> 2, ck = (idx & 3) * 8;
        *(uint4*)&Bs[0][0][rr][ck] = *(const uint4*)&Wtl[(size_t)rr * H1c + ck];
        *(uint4*)&Bs[0][1][rr][ck] = *(const uint4*)&Wtr[(size_t)rr * H1c + ck];
    }
    __syncthreads();

    f32x4 acc[4][4];
#pragma unroll
    for (int a = 0; a < 4; a++)
#pragma unroll
        for (int c = 0; c < 4; c++) acc[a][c] = (f32x4){0.f, 0.f, 0.f, 0.f};

#pragma unroll
    for (int kt = 0; kt < 4; kt++) {
        int bf = kt & 1;
        if (kt < 3) {   // prefetch next B into other buffer (overlaps MFMA)
            int kn = (kt + 1) * 32;
            for (int idx = threadIdx.x; idx < 1024; idx += 512) {
                int rr = idx >> 2, ck = (idx & 3) * 8;
                *(uint4*)&Bs[bf ^ 1][0][rr][ck] =
                    *(const uint4*)&Wtl[(size_t)rr * H1c + kn + ck];
                *(uint4*)&Bs[bf ^ 1][1][rr][ck] =
                    *(const uint4*)&Wtr[(size_t)rr * H1c + kn + ck];
            }
        }
        short8 a[2][4], bfr[2][4];
#pragma unroll
        for (int s = 0; s < 2; s++)
#pragma unroll
            for (int mt = 0; mt < 4; mt++)
                a[s][mt] = *(const short8*)&As[s][kt][wr + mt * 16 + l16][quad * 8];
#pragma unroll
        for (int s = 0; s < 2; s++)
#pragma unroll
            for (int nt = 0; nt < 4; nt++)
                bfr[s][nt] = *(const short8*)&Bs[bf][s][wc + nt * 16 + l16][quad * 8];
#pragma unroll
        for (int mt = 0; mt < 4; mt++)
#pragma unroll
            for (int nt = 0; nt < 4; nt++) {
                acc[mt][nt] = __builtin_amdgcn_mfma_f32_16x16x32_bf16(
                    a[0][mt], bfr[0][nt], acc[mt][nt], 0, 0, 0);
                acc[mt][nt] = __builtin_amdgcn_mfma_f32_16x16x32_bf16(
                    a[1][mt], bfr[1][nt], acc[mt][nt], 0, 0, 0);
            }
        __syncthreads();
    }
    float s[4] = {0.f, 0.f, 0.f, 0.f}, sq[4] = {0.f, 0.f, 0.f, 0.f};
#pragma unroll
    for (int nt = 0; nt < 4; nt++) {
        int colx = wc + nt * 16 + l16;
        float bv = bias[colx];
#pragma unroll
        for (int mt = 0; mt < 4; mt++)
#pragma unroll
            for (int rr = 0; rr < 4; rr++) {
                int row = m0 + wr + mt * 16 + quad * 4 + rr;
                float ov = acc[mt][nt][rr] + bv;
                out[(size_t)row * H2c + colx] = f2bf(ov);
                s[nt] += ov; sq[nt] += ov * ov;
            }
    }
#pragma unroll
    for (int nt = 0; nt < 4; nt++) {
        float ss = s[nt], qq = sq[nt];
        ss += __shfl_down(ss, 16); qq += __shfl_down(qq, 16);
        ss += __shfl_down(ss, 32); qq += __shfl_down(qq, 32);
        if (quad == 0) {
            bsumS[wid & 1][wc + nt * 16 + l16] = ss;
            bsqS[wid & 1][wc + nt * 16 + l16] = qq;
        }
    }
    __syncthreads();
    if (threadIdx.x < 256) {
        int c = threadIdx.x;
        atomicAdd(&dsum[c], (double)(bsumS[0][c] + bsumS[1][c]));
        atomicAdd(&dsq[c], (double)(bsqS[0][c] + bsqS[1][c]));
    }
}

// ---- sel2pool: XCD-affine graph; LDS r-slice + svals + select + pool + readout ----
__global__ void __launch_bounds__(1024) sel2pool_kernel(
        const float* __restrict__ r, const float* __restrict__ root,
        const int* __restrict__ deg, const int* __restrict__ col,
        const float* __restrict__ brel, const ushort* __restrict__ h2,
        const double* __restrict__ dsum, const double* __restrict__ dsq,
        const float* __restrict__ g_, const float* __restrict__ b_,
        const float* __restrict__ Wlin, const float* __restrict__ blin,
        float* __restrict__ out) {
    __shared__ float rL[1024];
    __shared__ float svals[1024];
    __shared__ uint hist[257];
    __shared__ uint wsum[16];
    __shared__ uint s_b, s_rem;
    __shared__ int permL[512];
    __shared__ float tvL[512];
    __shared__ float sc[256], sh[256];
    __shared__ float part2[32][256];
    int g = ((blockIdx.x & 7) << 2) + (blockIdx.x >> 3);   // graph g -> XCD g/4
    int tid = threadIdx.x;
    int lane = tid & 63, wid = tid >> 6;
    int base = g * K1c;
    if (tid < 256) {
        int c = tid;
        double m = dsum[c] / (double)N1c;
        double var = dsq[c] / (double)N1c - m * m;
        float s = g_[c] * (float)(1.0 / sqrt(var + 1e-5));
        sc[c] = s; sh[c] = b_[c] - (float)m * s;
    }
    rL[tid] = r[base + tid];
    if (tid < 257) hist[tid] = 0;
    __syncthreads();
    {
        int node = base + tid;
        float acc = brel[0] + root[node];
        int e0 = node * SLAB, dg = deg[node];
        int4 c0 = *(const int4*)&col[e0];
        int4 c1 = *(const int4*)&col[e0 + 4];
        int nb[8] = {c0.x, c0.y, c0.z, c0.w, c1.x, c1.y, c1.z, c1.w};
#pragma unroll
        for (int q = 0; q < 8; q++)
            if (q < dg) acc += rL[nb[q] - base];
        for (int e = e0 + 8; e < e0 + dg; e++) acc += rL[col[e] - base];
        svals[tid] = acc;
    }
    __syncthreads();

    uint prefix = 0, himask = 0, rem = (uint)K2c;
    for (int shift = 24; shift >= 0; shift -= 8) {
        {
            uint kk = fkey(svals[tid]);
            if ((kk & himask) == prefix) atomicAdd(&hist[(kk >> shift) & 255], 1);
        }
        __syncthreads();
        if (tid < 64) {
            int L = tid;
            uint h0 = hist[4 * L], h1v = hist[4 * L + 1], h2v = hist[4 * L + 2],
                 h3 = hist[4 * L + 3];
            uint s3 = h3, s2 = h2v + s3, s1 = h1v + s2, s0 = h0 + s1;
            uint v = s0;
            for (int off = 1; off < 64; off <<= 1) {
                uint u = __shfl_down(v, off);
                if (L + off < 64) v += u;
            }
            uint above = v - s0;
            hist[4 * L] = s0 + above;
            hist[4 * L + 1] = s1 + above;
            hist[4 * L + 2] = s2 + above;
            hist[4 * L + 3] = s3 + above;
        }
        __syncthreads();
        if (tid < 256) {
            uint sb = hist[tid], sb1 = hist[tid + 1];
            if (sb >= rem && sb1 < rem) { s_b = (uint)tid; s_rem = rem - sb1; }
        }
        __syncthreads();
        prefix |= (s_b << shift);
        rem = s_rem;
        himask |= (0xFFu << shift);
        if (tid < 256) hist[tid] = 0;
        __syncthreads();
    }
    uint thr = prefix;
    uint tieM = rem;

    uint kk = fkey(svals[tid]);
    bool gt = kk > thr, eq = kk == thr;
    uint key = (gt ? 0x10000u : 0u) | (eq ? 1u : 0u);
    uint v = key;
    for (int off = 1; off < 64; off <<= 1) {
        uint u = __shfl_up(v, off);
        if (lane >= off) v += u;
    }
    if (lane == 63) wsum[wid] = v;
    __syncthreads();
    if (tid < 16) {
        uint w0 = wsum[tid], w = w0;
        for (int off = 1; off < 16; off <<= 1) {
            uint u = __shfl_up(w, off);
            if ((int)tid >= off) w += u;
        }
        wsum[tid] = w - w0;
    }
    __syncthreads();
    uint excl = (v - key) + wsum[wid];
    uint gbase = excl >> 16, ebase = excl & 0xFFFFu;
    if (gt || (eq && ebase < tieM)) {
        uint pos = gbase + min(ebase, tieM);
        permL[pos] = base + tid;
        tvL[pos] = tanhf(svals[tid]);
    }
    __syncthreads();

    // pool: 32 threads/row x uint4 (8ch), 32 rows in flight, 16 serial iters
    {
        int rl = tid & 31, rg = tid >> 5;
        float a[8] = {0.f, 0.f, 0.f, 0.f, 0.f, 0.f, 0.f, 0.f};
        for (int it = 0; it < 16; it++) {
            int j = rg + it * 32;
            int row = permL[j];
            float tv = tvL[j];
            uint4 hv = *(const uint4*)&h2[((size_t)row << 8) + rl * 8];
            float f[8];
            unpk8(hv, f);
#pragma unroll
            for (int q = 0; q < 8; q++) {
                int cc = rl * 8 + q;
                a[q] += fmaxf(f[q] * sc[cc] + sh[cc], 0.f) * tv;
            }
        }
#pragma unroll
        for (int q = 0; q < 8; q++) part2[rg][rl * 8 + q] = a[q];
    }
    __syncthreads();
    if (tid < 256) {
        float s = 0.f;
#pragma unroll
        for (int gg = 0; gg < 32; gg++) s += part2[gg][tid];
        float sv = fmaxf(s * (1.f / (float)K2c), 0.f);
        rL[tid] = sv * Wlin[tid * 2 + 0];
        rL[256 + tid] = sv * Wlin[tid * 2 + 1];
    }
    __syncthreads();
    for (int off = 128; off; off >>= 1) {
        if (tid < off) { rL[tid] += rL[tid + off]; rL[256 + tid] += rL[256 + tid + off]; }
        __syncthreads();
    }
    if (tid == 0) {
        float o0 = rL[0] + blin[0], o1 = rL[256] + blin[1];
        float m = fmaxf(o0, o1);
        float e0 = expf(o0 - m), e1 = expf(o1 - m);
        float inv = 1.f / (e0 + e1);
        out[g * 2 + 0] = e0 * inv;
        out[g * 2 + 1] = e1 * inv;
    }
}

extern "C" void kernel_launch(void* const* d_in, const int* in_sizes, int n_in,
                              void* d_out, int out_size, void* d_ws, size_t ws_size,
                              hipStream_t stream) {
    const float* x      = (const float*)d_in[0];
    const int*   ei     = (const int*)d_in[1];
    const int*   src    = ei;
    const int*   tgt    = ei + Ee;
    const float* W1l    = (const float*)d_in[3];
    const float* b1l    = (const float*)d_in[4];
    const float* W1r    = (const float*)d_in[5];
    const float* bn1g   = (const float*)d_in[6];
    const float* bn1b   = (const float*)d_in[7];
    const float* p1Wrel = (const float*)d_in[8];
    const float* p1brel = (const float*)d_in[9];
    const float* p1Wroot= (const float*)d_in[10];
    const float* W2l    = (const float*)d_in[11];
    const float* b2l    = (const float*)d_in[12];
    const float* W2r    = (const float*)d_in[13];
    const float* bn2g   = (const float*)d_in[14];
    const float* bn2b   = (const float*)d_in[15];
    const float* p2Wrel = (const float*)d_in[16];
    const float* p2brel = (const float*)d_in[17];
    const float* p2Wroot= (const float*)d_in[18];
    const float* Wlin   = (const float*)d_in[19];
    const float* blin   = (const float*)d_in[20];
    float* out = (float*)d_out;
    char* ws = (char*)d_ws;

    size_t o = 0;
    auto A = [&](size_t b) { size_t r = o; o += (b + 255) & ~(size_t)255; return r; };
    size_t oH1   = A((size_t)Nn * H1c * 2);        // h1 bf16 (live through gemm2f)
    size_t oH2   = A((size_t)N1c * H2c * 2);       // h2 bf16
    size_t oCol1 = A((size_t)Nn * SLAB * 4);
    size_t oCol2 = A((size_t)N1c * SLAB * 4);
    size_t oWc1  = A((size_t)Nn * 4);
    size_t oR1   = A((size_t)Nn * 4);
    size_t oRoot1= A((size_t)Nn * 4);
    size_t oMap1 = A((size_t)Nn * 4);
    size_t oPerm1= A((size_t)N1c * 4);
    size_t oTv1  = A((size_t)N1c * 4);
    size_t oWc2  = A((size_t)N1c * 4);
    size_t oR2   = A((size_t)N1c * 4);
    size_t oRoot2= A((size_t)N1c * 4);
    size_t oDst  = A(768 * 8);
    size_t oWt1l = A(8192 * 2);
    size_t oWt1r = A(8192 * 2);
    size_t oWt2l = A(32768 * 2);
    size_t oWt2r = A(32768 * 2);
    (void)ws_size; (void)in_sizes; (void)n_in; (void)out_size;

    ushort* h1   = (ushort*)(ws + oH1);
    ushort* h2   = (ushort*)(ws + oH2);
    int* col1    = (int*)(ws + oCol1);
    int* col2    = (int*)(ws + oCol2);
    int* wc1     = (int*)(ws + oWc1);
    float* r1    = (float*)(ws + oR1);
    float* root1 = (float*)(ws + oRoot1);
    int* map1    = (int*)(ws + oMap1);
    int* perm1   = (int*)(ws + oPerm1);
    float* tv1   = (float*)(ws + oTv1);
    int* wc2     = (int*)(ws + oWc2);
    float* r2    = (float*)(ws + oR2);
    float* root2 = (float*)(ws + oRoot2);
    double* dsum1= (double*)(ws + oDst);
    double* dsq1 = dsum1 + 128;
    double* dsum2= dsum1 + 256;
    double* dsq2 = dsum1 + 512;
    ushort* T1l  = (ushort*)(ws + oWt1l);
    ushort* T1r  = (ushort*)(ws + oWt1r);
    ushort* T2l  = (ushort*)(ws + oWt2l);
    ushort* T2r  = (ushort*)(ws + oWt2r);

    // 1. init zeros (wc1, BN stats)
    init_kernel<<<(INIT_TOTAL + 255) / 256, 256, 0, stream>>>(
        (int4*)wc1, (int4*)dsum1);

    // 2. fused: fill1 || weight transposes
    prep2_kernel<<<PREP2_TOTAL / 256, 256, 0, stream>>>(
        src, tgt, W1l, W1r, W2l, W2r, T1l, T1r, T2l, T2r, wc1, col1);

    // 3. fused agg1 + GEMM1 from f32 x (+ BN1 stats), full-K staged
    gemm1f_kernel<<<512, 512, 0, stream>>>(x, wc1, col1, T1l, T1r, b1l, h1,
                                           dsum1, dsq1);

    // 4. score1 full-grid (r1/root1), XCD-affine
    score_kernel<H1c><<<Nn / 32, 256, 0, stream>>>(h1, dsum1, dsq1, bn1g, bn1b, p1Wrel,
                                                   p1Wroot, r1, root1, Nn, NPGc);

    // 5. svals + radix select (+ map), XCD-affine
    sel1_kernel<<<Bg, 1024, 0, stream>>>(r1, root1, wc1, col1, p1brel, perm1, tv1, map1);

    // 6. node-parallel layer2 slab derivation (no atomics)
    nofill2_kernel<<<N1c / 256, 256, 0, stream>>>(perm1, map1, wc1, col1, wc2, col2);

    // 7. fused BN1-apply + agg2 + GEMM2 (+ BN2 stats), full-K A staged
    gemm2f_kernel<<<256, 512, 0, stream>>>(h1, perm1, tv1, dsum1, dsq1, bn1g, bn1b,
                                           wc2, col2, T2l, T2r, b2l, h2, dsum2, dsq2);

    // 8. score2 full-grid (r2/root2), XCD-affine
    score_kernel<H2c><<<N1c / 32, 256, 0, stream>>>(h2, dsum2, dsq2, bn2g, bn2b, p2Wrel,
                                                    p2Wroot, r2, root2, N1c, K1c);

    // 9. svals2 + select + pool + readout, XCD-affine
    sel2pool_kernel<<<Bg, 1024, 0, stream>>>(r2, root2, wc2, col2, p2brel, h2, dsum2,
                                             dsq2, bn2g, bn2b, Wlin, blin, out);
}

// Round 12
// 213.171 us; speedup vs baseline: 1.6285x; 1.0209x over previous
//
#include <hip/hip_runtime.h>
#include <math.h>

#define Bg   32
#define NPGc 2048
#define Nn   (Bg*NPGc)      // 65536
#define DEGc 8
#define Ee   (Nn*DEGc)      // 524288
#define INc  64
#define H1c  128
#define H2c  256
#define K1c  1024
#define K2c  512
#define N1c  (Bg*K1c)       // 32768
#define N2c  (Bg*K2c)       // 16384
#define SLAB 64             // fixed CSR slab per node

typedef __attribute__((ext_vector_type(8))) short short8;
typedef __attribute__((ext_vector_type(4))) float f32x4;

__device__ __forceinline__ ushort f2bf(float f) {
    uint u = __float_as_uint(f);
    uint r = (u + 0x7fffu + ((u >> 16) & 1u)) >> 16;
    return (ushort)r;
}
__device__ __forceinline__ float bf2f(ushort v) { return __uint_as_float((uint)v << 16); }
__device__ __forceinline__ float bfhi(uint v) { return __uint_as_float(v & 0xffff0000u); }
__device__ __forceinline__ float bflo(uint v) { return __uint_as_float(v << 16); }
__device__ __forceinline__ uint fkey(float f) {
    uint u = __float_as_uint(f);
    return u ^ ((uint)((int)u >> 31) | 0x80000000u);
}
__device__ __forceinline__ void unpk8(uint4 v, float* f) {
    f[0] = bflo(v.x); f[1] = bfhi(v.x);
    f[2] = bflo(v.y); f[3] = bfhi(v.y);
    f[4] = bflo(v.z); f[5] = bfhi(v.z);
    f[6] = bflo(v.w); f[7] = bfhi(v.w);
}
__device__ __forceinline__ uint4 pack8(const float* a, float inv) {
    uint4 o;
    o.x = (uint)f2bf(a[0] * inv) | ((uint)f2bf(a[1] * inv) << 16);
    o.y = (uint)f2bf(a[2] * inv) | ((uint)f2bf(a[3] * inv) << 16);
    o.z = (uint)f2bf(a[4] * inv) | ((uint)f2bf(a[5] * inv) << 16);
    o.w = (uint)f2bf(a[6] * inv) | ((uint)f2bf(a[7] * inv) << 16);
    return o;
}
__device__ __forceinline__ void accf8(float* a, const float* p) {
    float4 u0 = *(const float4*)p;
    float4 u1 = *(const float4*)(p + 4);
    a[0] += u0.x; a[1] += u0.y; a[2] += u0.z; a[3] += u0.w;
    a[4] += u1.x; a[5] += u1.y; a[6] += u1.z; a[7] += u1.w;
}

// ---------------- init: zero wc1/stats ----------------
__global__ void init_kernel(int4* __restrict__ wc1, int4* __restrict__ dstats) {
    int id = blockIdx.x * blockDim.x + threadIdx.x;
    int4 z = {0, 0, 0, 0};
    if (id < 16384) { wc1[id] = z; return; }
    id -= 16384;
    if (id < 384)   { dstats[id] = z; }
}
#define INIT_TOTAL (16384 + 384)

// ------- prep2: fill1 (slab CSR) || weight transposes, grid-partitioned -------
__global__ void prep2_kernel(const int* __restrict__ src, const int* __restrict__ tgt,
                             const float* __restrict__ W1l, const float* __restrict__ W1r,
                             const float* __restrict__ W2l, const float* __restrict__ W2r,
                             ushort* __restrict__ T1l, ushort* __restrict__ T1r,
                             ushort* __restrict__ T2l, ushort* __restrict__ T2r,
                             int* __restrict__ wc1, int* __restrict__ col1) {
    int id = blockIdx.x * blockDim.x + threadIdx.x;
    if (id < Ee) {
        int t = tgt[id];
        int p = atomicAdd(&wc1[t], 1);
        col1[t * SLAB + p] = src[id];
        return;
    }
    id -= Ee;
    if (id < 8192) {
        int c = id / 64, k = id % 64;
        T1l[id] = f2bf(W1l[k * 128 + c]);
        T1r[id] = f2bf(W1r[k * 128 + c]);
        return;
    }
    id -= 8192;
    if (id < 32768) {
        int c = id / 128, k = id % 128;
        T2l[id] = f2bf(W2l[k * 256 + c]);
        T2r[id] = f2bf(W2r[k * 256 + c]);
    }
}
#define PREP2_TOTAL (Ee + 8192 + 32768)

// ---- gemm1f: fused agg1 + SAGEConv1 GEMM from f32 x, full-K staged, 1 barrier ----
__global__ __launch_bounds__(512) void gemm1f_kernel(
        const float* __restrict__ x, const int* __restrict__ deg,
        const int* __restrict__ col, const ushort* __restrict__ Wtl,
        const ushort* __restrict__ Wtr, const float* __restrict__ bias,
        ushort* __restrict__ out, double* __restrict__ dsum,
        double* __restrict__ dsq) {
    __shared__ ushort As[2][2][128][36];   // [src][kt][row][ch]
    __shared__ ushort Bs[2][2][128][36];   // full B
    __shared__ float bsumS[2][128], bsqS[2][128];
    int b = blockIdx.x;
    int bs = ((b & 7) << 6) + (b >> 3);    // graph g -> XCD g/4
    int m0 = bs << 7;
    int lane = threadIdx.x & 63;
    int wid = threadIdx.x >> 6;
    int wr = (wid & 1) << 6, wc = (wid >> 1) << 5;
    int l16 = lane & 15, quad = lane >> 4;

    int ar = threadIdx.x >> 2, ack = (threadIdx.x & 3) * 8;
    int anode = m0 + ar;
    int abg = anode * SLAB, adg = deg[anode];
    int4 c0h = *(const int4*)&col[abg];
    int4 c1h = *(const int4*)&col[abg + 4];
    int anb[8] = {c0h.x, c0h.y, c0h.z, c0h.w, c1h.x, c1h.y, c1h.z, c1h.w};

    {   // B full stage
        int r = threadIdx.x >> 2, ck = (threadIdx.x & 3) * 8;
#pragma unroll
        for (int kt = 0; kt < 2; kt++) {
            *(uint4*)&Bs[0][kt][r][ck] = *(const uint4*)&Wtl[(size_t)r * INc + kt * 32 + ck];
            *(uint4*)&Bs[1][kt][r][ck] = *(const uint4*)&Wtr[(size_t)r * INc + kt * 32 + ck];
        }
    }
    {   // A own row (f32 -> bf16), both k-slices
#pragma unroll
        for (int kt = 0; kt < 2; kt++) {
            const float* xp = &x[(size_t)anode * INc + kt * 32 + ack];
            float vals[8];
            float4 v0 = *(const float4*)xp, v1 = *(const float4*)(xp + 4);
            vals[0] = v0.x; vals[1] = v0.y; vals[2] = v0.z; vals[3] = v0.w;
            vals[4] = v1.x; vals[5] = v1.y; vals[6] = v1.z; vals[7] = v1.w;
            *(uint4*)&As[1][kt][ar][ack] = pack8(vals, 1.f);
        }
    }
    {   // A agg: all neighbor gathers up front, both k-slices
        float aacc[2][8];
#pragma unroll
        for (int kt = 0; kt < 2; kt++)
#pragma unroll
            for (int q = 0; q < 8; q++) aacc[kt][q] = 0.f;
#pragma unroll
        for (int j = 0; j < 8; j++)
            if (j < adg) {
                const float* xp = &x[(size_t)anb[j] * INc + ack];
#pragma unroll
                for (int kt = 0; kt < 2; kt++) accf8(aacc[kt], xp + kt * 32);
            }
        for (int i = abg + 8; i < abg + adg; i++) {
            const float* xp = &x[(size_t)col[i] * INc + ack];
#pragma unroll
            for (int kt = 0; kt < 2; kt++) accf8(aacc[kt], xp + kt * 32);
        }
        int cdg = adg < 1 ? 1 : adg;
        float inv = 1.f / (float)cdg;
#pragma unroll
        for (int kt = 0; kt < 2; kt++)
            *(uint4*)&As[0][kt][ar][ack] = pack8(aacc[kt], inv);
    }
    __syncthreads();

    f32x4 acc[4][2];
#pragma unroll
    for (int a = 0; a < 4; a++)
#pragma unroll
        for (int c = 0; c < 2; c++) acc[a][c] = (f32x4){0.f, 0.f, 0.f, 0.f};

#pragma unroll
    for (int kt = 0; kt < 2; kt++) {
        short8 a[2][4], bfr[2][2];
#pragma unroll
        for (int s = 0; s < 2; s++)
#pragma unroll
            for (int mt = 0; mt < 4; mt++)
                a[s][mt] = *(const short8*)&As[s][kt][wr + mt * 16 + l16][quad * 8];
#pragma unroll
        for (int s = 0; s < 2; s++)
#pragma unroll
            for (int nt = 0; nt < 2; nt++)
                bfr[s][nt] = *(const short8*)&Bs[s][kt][wc + nt * 16 + l16][quad * 8];
#pragma unroll
        for (int mt = 0; mt < 4; mt++)
#pragma unroll
            for (int nt = 0; nt < 2; nt++) {
                acc[mt][nt] = __builtin_amdgcn_mfma_f32_16x16x32_bf16(
                    a[0][mt], bfr[0][nt], acc[mt][nt], 0, 0, 0);
                acc[mt][nt] = __builtin_amdgcn_mfma_f32_16x16x32_bf16(
                    a[1][mt], bfr[1][nt], acc[mt][nt], 0, 0, 0);
            }
    }
    float s[2] = {0.f, 0.f}, sq[2] = {0.f, 0.f};
#pragma unroll
    for (int nt = 0; nt < 2; nt++) {
        int colx = wc + nt * 16 + l16;
        float bv = bias[colx];
#pragma unroll
        for (int mt = 0; mt < 4; mt++)
#pragma unroll
            for (int rr = 0; rr < 4; rr++) {
                int row = m0 + wr + mt * 16 + quad * 4 + rr;
                float ov = acc[mt][nt][rr] + bv;
                out[(size_t)row * H1c + colx] = f2bf(ov);
                s[nt] += ov; sq[nt] += ov * ov;
            }
    }
#pragma unroll
    for (int nt = 0; nt < 2; nt++) {
        float ss = s[nt], qq = sq[nt];
        ss += __shfl_down(ss, 16); qq += __shfl_down(qq, 16);
        ss += __shfl_down(ss, 32); qq += __shfl_down(qq, 32);
        if (quad == 0) {
            bsumS[wid & 1][wc + nt * 16 + l16] = ss;
            bsqS[wid & 1][wc + nt * 16 + l16] = qq;
        }
    }
    __syncthreads();
    if (threadIdx.x < 128) {
        int c = threadIdx.x;
        atomicAdd(&dsum[c], (double)(bsumS[0][c] + bsumS[1][c]));
        atomicAdd(&dsq[c], (double)(bsqS[0][c] + bsqS[1][c]));
    }
}

// ------- score: full-grid, 8 lanes/node, XCD-affine block swizzle -------
template<int C>
__global__ __launch_bounds__(256) void score_kernel(const ushort* __restrict__ h,
                                                    const double* __restrict__ dsum,
                                                    const double* __restrict__ dsq,
                                                    const float* __restrict__ g,
                                                    const float* __restrict__ b,
                                                    const float* __restrict__ wrel,
                                                    const float* __restrict__ wroot,
                                                    float* __restrict__ r,
                                                    float* __restrict__ root,
                                                    int n, int npg) {
    __shared__ float sc[C], sh[C], wrl[C], wrt[C];
    if ((int)threadIdx.x < C) {
        int c = threadIdx.x;
        double m = dsum[c] / (double)n;
        double var = dsq[c] / (double)n - m * m;
        float s = g[c] * (float)(1.0 / sqrt(var + 1e-5));
        sc[c] = s; sh[c] = b[c] - (float)m * s;
        wrl[c] = wrel[c]; wrt[c] = wroot[c];
    }
    __syncthreads();
    int bid = blockIdx.x;
    int xcd = bid & 7, t = bid >> 3;
    int gg = xcd * 4 + (t & 3);        // graph -> XCD graph/4
    int j = t >> 2;                    // block within graph
    int node = gg * npg + j * 32 + ((int)threadIdx.x >> 3);
    int ln = threadIdx.x & 7;
    float rr = 0.f, rt = 0.f;
#pragma unroll
    for (int p = 0; p < C / 64; p++) {
        int cb = p * 64 + ln * 8;
        uint4 v = *(const uint4*)&h[(size_t)node * C + cb];
        float vv[8];
        unpk8(v, vv);
#pragma unroll
        for (int q = 0; q < 8; q++) {
            int cc = cb + q;
            float val = fmaxf(vv[q] * sc[cc] + sh[cc], 0.f);
            rr += val * wrl[cc];
            rt += val * wrt[cc];
        }
    }
#pragma unroll
    for (int off = 4; off; off >>= 1) {
        rr += __shfl_down(rr, off);
        rt += __shfl_down(rt, off);
    }
    if (ln == 0) { r[node] = rr; root[node] = rt; }
}

// ---- sel1: LDS r-slice + svals + radix select + perm/tv + fused layer2 CSR build ----
__global__ void __launch_bounds__(1024) sel1_kernel(const float* __restrict__ r,
                                                    const float* __restrict__ root,
                                                    const int* __restrict__ deg,
                                                    const int* __restrict__ col,
                                                    const float* __restrict__ brel,
                                                    int* __restrict__ perm,
                                                    float* __restrict__ tval,
                                                    int* __restrict__ wc2,
                                                    int* __restrict__ col2) {
    __shared__ float rL[2048];
    __shared__ float svals[2048];
    __shared__ uint hist[257];
    __shared__ uint wsum[16];
    __shared__ uint s_b, s_rem;
    __shared__ int mapL[2048];
    __shared__ int oldL[1024];
    int g = ((blockIdx.x & 7) << 2) + (blockIdx.x >> 3);   // graph g -> XCD g/4
    int tid = threadIdx.x;
    int lane = tid & 63, wid = tid >> 6;
    int base = g * NPGc;
    rL[tid] = r[base + tid];
    rL[tid + 1024] = r[base + tid + 1024];
    if (tid < 257) hist[tid] = 0;
    __syncthreads();
    float bv = brel[0];
#pragma unroll
    for (int j = 0; j < 2; j++) {
        int i = tid + (j << 10);
        int node = base + i;
        float acc = bv + root[node];
        int e0 = node * SLAB, dg = deg[node];
        int4 c0 = *(const int4*)&col[e0];
        int4 c1 = *(const int4*)&col[e0 + 4];
        int nb[8] = {c0.x, c0.y, c0.z, c0.w, c1.x, c1.y, c1.z, c1.w};
#pragma unroll
        for (int q = 0; q < 8; q++)
            if (q < dg) acc += rL[nb[q] - base];
        for (int e = e0 + 8; e < e0 + dg; e++) acc += rL[col[e] - base];
        svals[i] = acc;
    }
    __syncthreads();

    uint prefix = 0, himask = 0, rem = (uint)K1c;
    for (int shift = 24; shift >= 0; shift -= 8) {
#pragma unroll
        for (int j = 0; j < 2; j++) {
            uint kk = fkey(svals[tid + (j << 10)]);
            if ((kk & himask) == prefix) atomicAdd(&hist[(kk >> shift) & 255], 1);
        }
        __syncthreads();
        if (tid < 64) {
            int L = tid;
            uint h0 = hist[4 * L], h1v = hist[4 * L + 1], h2v = hist[4 * L + 2],
                 h3 = hist[4 * L + 3];
            uint s3 = h3, s2 = h2v + s3, s1 = h1v + s2, s0 = h0 + s1;
            uint v = s0;
            for (int off = 1; off < 64; off <<= 1) {
                uint u = __shfl_down(v, off);
                if (L + off < 64) v += u;
            }
            uint above = v - s0;
            hist[4 * L] = s0 + above;
            hist[4 * L + 1] = s1 + above;
            hist[4 * L + 2] = s2 + above;
            hist[4 * L + 3] = s3 + above;
        }
        __syncthreads();
        if (tid < 256) {
            uint sb = hist[tid], sb1 = hist[tid + 1];
            if (sb >= rem && sb1 < rem) { s_b = (uint)tid; s_rem = rem - sb1; }
        }
        __syncthreads();
        prefix |= (s_b << shift);
        rem = s_rem;
        himask |= (0xFFu << shift);
        if (tid < 256) hist[tid] = 0;
        __syncthreads();
    }
    uint thr = prefix;
    uint tieM = rem;
    uint gcnt = 0, ecnt = 0, gflags = 0, eflags = 0;
#pragma unroll
    for (int j = 0; j < 2; j++) {
        uint kk = fkey(svals[tid + (j << 10)]);
        if (kk > thr) { gflags |= 1u << j; gcnt++; }
        else if (kk == thr) { eflags |= 1u << j; ecnt++; }
    }
    uint key = (gcnt << 16) | ecnt;
    uint v = key;
    for (int off = 1; off < 64; off <<= 1) {
        uint u = __shfl_up(v, off);
        if (lane >= off) v += u;
    }
    if (lane == 63) wsum[wid] = v;
    __syncthreads();
    if (tid < 16) {
        uint w0 = wsum[tid], w = w0;
        for (int off = 1; off < 16; off <<= 1) {
            uint u = __shfl_up(w, off);
            if ((int)tid >= off) w += u;
        }
        wsum[tid] = w - w0;
    }
    __syncthreads();
    uint excl = (v - key) + wsum[wid];
    uint gbase = excl >> 16, ebase = excl & 0xFFFFu;
#pragma unroll
    for (int j = 0; j < 2; j++) {
        bool gt = (gflags >> j) & 1u;
        bool eq = (eflags >> j) & 1u;
        int i = tid + (j << 10);
        int o = -1;
        if (gt || (eq && ebase < tieM)) {
            uint pos = gbase + min(ebase, tieM);
            o = g * K1c + (int)pos;
            perm[o] = base + i;
            tval[o] = tanhf(svals[i]);
            oldL[pos] = i;
        }
        mapL[i] = o;
        gbase += gt ? 1u : 0u;
        ebase += eq ? 1u : 0u;
    }
    __syncthreads();
    // fused nofill2: thread p handles kept position p (exactly K1c kept)
    {
        int p = tid;
        int i = oldL[p];
        int node = base + i;
        int e0 = node * SLAB, dg = deg[node];
        int4 cc0 = *(const int4*)&col[e0];
        int4 cc1 = *(const int4*)&col[e0 + 4];
        int nb[8] = {cc0.x, cc0.y, cc0.z, cc0.w, cc1.x, cc1.y, cc1.z, cc1.w};
        int cnt = 0;
        int newid = g * K1c + p;
        int ob = newid * SLAB;
#pragma unroll
        for (int q = 0; q < 8; q++)
            if (q < dg) {
                int m = mapL[nb[q] - base];
                if (m >= 0) col2[ob + cnt++] = m;
            }
        for (int e = e0 + 8; e < e0 + dg; e++) {
            int m = mapL[col[e] - base];
            if (m >= 0) col2[ob + cnt++] = m;
        }
        wc2[newid] = cnt;
    }
}

// ---- gemm2f: fused BN1-apply/tanh + agg2 + SAGEConv2 GEMM, full-K A staged ----
__global__ __launch_bounds__(512) void gemm2f_kernel(
        const ushort* __restrict__ h1, const int* __restrict__ perm1,
        const float* __restrict__ tv1, const double* __restrict__ dsum1,
        const double* __restrict__ dsq1, const float* __restrict__ bn1g,
        const float* __restrict__ bn1b, const int* __restrict__ deg,
        const int* __restrict__ col, const ushort* __restrict__ Wtl,
        const ushort* __restrict__ Wtr, const float* __restrict__ bias,
        ushort* __restrict__ out, double* __restrict__ dsum,
        double* __restrict__ dsq) {
    __shared__ ushort As[2][4][128][36];       // [src][kt][row][ch]  73.7 KB
    __shared__ ushort Bs[2][2][256][36];       // [buf][src][row][ch] 73.7 KB
    __shared__ float bsumS[2][256], bsqS[2][256];
    __shared__ float sc1[128], sh1[128];
    int b = blockIdx.x;
    int bs = ((b & 7) << 5) + (b >> 3);        // graph g -> XCD g/4
    int m0 = bs << 7;
    int lane = threadIdx.x & 63;
    int wid = threadIdx.x >> 6;
    int wr = (wid & 1) << 6, wc = (wid >> 1) << 6;
    int l16 = lane & 15, quad = lane >> 4;

    if (threadIdx.x < 128) {
        int c = threadIdx.x;
        double m = dsum1[c] / (double)Nn;
        double var = dsq1[c] / (double)Nn - m * m;
        float s = bn1g[c] * (float)(1.0 / sqrt(var + 1e-5));
        sc1[c] = s; sh1[c] = bn1b[c] - (float)m * s;
    }

    // hoisted per-thread A-staging indices (col2: new-id CSR)
    int ar = threadIdx.x >> 2, ack = (threadIdx.x & 3) * 8;
    int anode = m0 + ar;
    int aold = perm1[anode];
    float atv = tv1[anode];
    int abg = anode * SLAB, adg = deg[anode];
    int4 c0h = *(const int4*)&col[abg];
    int4 c1h = *(const int4*)&col[abg + 4];
    int anb[8] = {c0h.x, c0h.y, c0h.z, c0h.w, c1h.x, c1h.y, c1h.z, c1h.w};
    int aon[8]; float atn[8];
#pragma unroll
    for (int j = 0; j < 8; j++) {
        int nbv = (j < adg) ? anb[j] : anode;  // guard poison entries
        aon[j] = perm1[nbv];
        atn[j] = tv1[nbv];
    }
    __syncthreads();   // sc1/sh1 ready

    {   // A own row: all 4 k-slices, BN-relu-tanh transformed
#pragma unroll
        for (int kt = 0; kt < 4; kt++) {
            uint4 hv = *(const uint4*)&h1[((size_t)aold << 7) + kt * 32 + ack];
            float vals[8];
            unpk8(hv, vals);
#pragma unroll
            for (int q = 0; q < 8; q++) {
                int cc = kt * 32 + ack + q;
                vals[q] = fmaxf(vals[q] * sc1[cc] + sh1[cc], 0.f) * atv;
            }
            *(uint4*)&As[1][kt][ar][ack] = pack8(vals, 1.f);
        }
    }
    {   // A agg: all neighbor gathers (all k-slices) up front
        float aacc[4][8];
#pragma unroll
        for (int kt = 0; kt < 4; kt++)
#pragma unroll
            for (int q = 0; q < 8; q++) aacc[kt][q] = 0.f;
#pragma unroll
        for (int j = 0; j < 8; j++)
            if (j < adg) {
                const ushort* hp = &h1[(size_t)aon[j] << 7];
                float tn = atn[j];
#pragma unroll
                for (int kt = 0; kt < 4; kt++) {
                    uint4 u = *(const uint4*)&hp[kt * 32 + ack];
                    float f[8];
                    unpk8(u, f);
#pragma unroll
                    for (int q = 0; q < 8; q++) {
                        int cc = kt * 32 + ack + q;
                        aacc[kt][q] += fmaxf(f[q] * sc1[cc] + sh1[cc], 0.f) * tn;
                    }
                }
            }
        for (int i = abg + 8; i < abg + adg; i++) {
            int nbv = col[i];
            int on = perm1[nbv];
            float tn = tv1[nbv];
            const ushort* hp = &h1[(size_t)on << 7];
#pragma unroll
            for (int kt = 0; kt < 4; kt++) {
                uint4 u = *(const uint4*)&hp[kt * 32 + ack];
                float f[8];
                unpk8(u, f);
#pragma unroll
                for (int q = 0; q < 8; q++) {
                    int cc = kt * 32 + ack + q;
                    aacc[kt][q] += fmaxf(f[q] * sc1[cc] + sh1[cc], 0.f) * tn;
                }
            }
        }
        int cdg = adg < 1 ? 1 : adg;
        float inv = 1.f / (float)cdg;
#pragma unroll
        for (int kt = 0; kt < 4; kt++)
            *(uint4*)&As[0][kt][ar][ack] = pack8(aacc[kt], inv);
    }
    // B stage for k-step 0 into buffer 0
    for (int idx = threadIdx.x; idx < 1024; idx += 512) {
        int rr = idx >> 2, ck = (idx & 3) * 8;
        *(uint4*)&Bs[0][0][rr][ck] = *(const uint4*)&Wtl[(size_t)rr * H1c + ck];
        *(uint4*)&Bs[0][1][rr][ck] = *(const uint4*)&Wtr[(size_t)rr * H1c + ck];
    }
    __syncthreads();

    f32x4 acc[4][4];
#pragma unroll
    for (int a = 0; a < 4; a++)
#pragma unroll
        for (int c = 0; c < 4; c++) acc[a][c] = (f32x4){0.f, 0.f, 0.f, 0.f};

#pragma unroll
    for (int kt = 0; kt < 4; kt++) {
        int bf = kt & 1;
        if (kt < 3) {   // prefetch next B into other buffer (overlaps MFMA)
            int kn = (kt + 1) * 32;
            for (int idx = threadIdx.x; idx < 1024; idx += 512) {
                int rr = idx >> 2, ck = (idx & 3) * 8;
                *(uint4*)&Bs[bf ^ 1][0][rr][ck] =
                    *(const uint4*)&Wtl[(size_t)rr * H1c + kn + ck];
                *(uint4*)&Bs[bf ^ 1][1][rr][ck] =
                    *(const uint4*)&Wtr[(size_t)rr * H1c + kn + ck];
            }
        }
        short8 a[2][4], bfr[2][4];
#pragma unroll
        for (int s = 0; s < 2; s++)
#pragma unroll
            for (int mt = 0; mt < 4; mt++)
                a[s][mt] = *(const short8*)&As[s][kt][wr + mt * 16 + l16][quad * 8];
#pragma unroll
        for (int s = 0; s < 2; s++)
#pragma unroll
            for (int nt = 0; nt < 4; nt++)
                bfr[s][nt] = *(const short8*)&Bs[bf][s][wc + nt * 16 + l16][quad * 8];
#pragma unroll
        for (int mt = 0; mt < 4; mt++)
#pragma unroll
            for (int nt = 0; nt < 4; nt++) {
                acc[mt][nt] = __builtin_amdgcn_mfma_f32_16x16x32_bf16(
                    a[0][mt], bfr[0][nt], acc[mt][nt], 0, 0, 0);
                acc[mt][nt] = __builtin_amdgcn_mfma_f32_16x16x32_bf16(
                    a[1][mt], bfr[1][nt], acc[mt][nt], 0, 0, 0);
            }
        __syncthreads();
    }
    float s[4] = {0.f, 0.f, 0.f, 0.f}, sq[4] = {0.f, 0.f, 0.f, 0.f};
#pragma unroll
    for (int nt = 0; nt < 4; nt++) {
        int colx = wc + nt * 16 + l16;
        float bv = bias[colx];
#pragma unroll
        for (int mt = 0; mt < 4; mt++)
#pragma unroll
            for (int rr = 0; rr < 4; rr++) {
                int row = m0 + wr + mt * 16 + quad * 4 + rr;
                float ov = acc[mt][nt][rr] + bv;
                out[(size_t)row * H2c + colx] = f2bf(ov);
                s[nt] += ov; sq[nt] += ov * ov;
            }
    }
#pragma unroll
    for (int nt = 0; nt < 4; nt++) {
        float ss = s[nt], qq = sq[nt];
        ss += __shfl_down(ss, 16); qq += __shfl_down(qq, 16);
        ss += __shfl_down(ss, 32); qq += __shfl_down(qq, 32);
        if (quad == 0) {
            bsumS[wid & 1][wc + nt * 16 + l16] = ss;
            bsqS[wid & 1][wc + nt * 16 + l16] = qq;
        }
    }
    __syncthreads();
    if (threadIdx.x < 256) {
        int c = threadIdx.x;
        atomicAdd(&dsum[c], (double)(bsumS[0][c] + bsumS[1][c]));
        atomicAdd(&dsq[c], (double)(bsqS[0][c] + bsqS[1][c]));
    }
}

// ---- sel2pool: XCD-affine graph; LDS r-slice + svals + select + pool + readout ----
__global__ void __launch_bounds__(1024) sel2pool_kernel(
        const float* __restrict__ r, const float* __restrict__ root,
        const int* __restrict__ deg, const int* __restrict__ col,
        const float* __restrict__ brel, const ushort* __restrict__ h2,
        const double* __restrict__ dsum, const double* __restrict__ dsq,
        const float* __restrict__ g_, const float* __restrict__ b_,
        const float* __restrict__ Wlin, const float* __restrict__ blin,
        float* __restrict__ out) {
    __shared__ float rL[1024];
    __shared__ float svals[1024];
    __shared__ uint hist[257];
    __shared__ uint wsum[16];
    __shared__ uint s_b, s_rem;
    __shared__ int permL[512];
    __shared__ float tvL[512];
    __shared__ float sc[256], sh[256];
    __shared__ float part2[32][256];
    int g = ((blockIdx.x & 7) << 2) + (blockIdx.x >> 3);   // graph g -> XCD g/4
    int tid = threadIdx.x;
    int lane = tid & 63, wid = tid >> 6;
    int base = g * K1c;
    if (tid < 256) {
        int c = tid;
        double m = dsum[c] / (double)N1c;
        double var = dsq[c] / (double)N1c - m * m;
        float s = g_[c] * (float)(1.0 / sqrt(var + 1e-5));
        sc[c] = s; sh[c] = b_[c] - (float)m * s;
    }
    rL[tid] = r[base + tid];
    if (tid < 257) hist[tid] = 0;
    __syncthreads();
    {
        int node = base + tid;
        float acc = brel[0] + root[node];
        int e0 = node * SLAB, dg = deg[node];
        int4 c0 = *(const int4*)&col[e0];
        int4 c1 = *(const int4*)&col[e0 + 4];
        int nb[8] = {c0.x, c0.y, c0.z, c0.w, c1.x, c1.y, c1.z, c1.w};
#pragma unroll
        for (int q = 0; q < 8; q++)
            if (q < dg) acc += rL[nb[q] - base];
        for (int e = e0 + 8; e < e0 + dg; e++) acc += rL[col[e] - base];
        svals[tid] = acc;
    }
    __syncthreads();

    uint prefix = 0, himask = 0, rem = (uint)K2c;
    for (int shift = 24; shift >= 0; shift -= 8) {
        {
            uint kk = fkey(svals[tid]);
            if ((kk & himask) == prefix) atomicAdd(&hist[(kk >> shift) & 255], 1);
        }
        __syncthreads();
        if (tid < 64) {
            int L = tid;
            uint h0 = hist[4 * L], h1v = hist[4 * L + 1], h2v = hist[4 * L + 2],
                 h3 = hist[4 * L + 3];
            uint s3 = h3, s2 = h2v + s3, s1 = h1v + s2, s0 = h0 + s1;
            uint v = s0;
            for (int off = 1; off < 64; off <<= 1) {
                uint u = __shfl_down(v, off);
                if (L + off < 64) v += u;
            }
            uint above = v - s0;
            hist[4 * L] = s0 + above;
            hist[4 * L + 1] = s1 + above;
            hist[4 * L + 2] = s2 + above;
            hist[4 * L + 3] = s3 + above;
        }
        __syncthreads();
        if (tid < 256) {
            uint sb = hist[tid], sb1 = hist[tid + 1];
            if (sb >= rem && sb1 < rem) { s_b = (uint)tid; s_rem = rem - sb1; }
        }
        __syncthreads();
        prefix |= (s_b << shift);
        rem = s_rem;
        himask |= (0xFFu << shift);
        if (tid < 256) hist[tid] = 0;
        __syncthreads();
    }
    uint thr = prefix;
    uint tieM = rem;

    uint kk = fkey(svals[tid]);
    bool gt = kk > thr, eq = kk == thr;
    uint key = (gt ? 0x10000u : 0u) | (eq ? 1u : 0u);
    uint v = key;
    for (int off = 1; off < 64; off <<= 1) {
        uint u = __shfl_up(v, off);
        if (lane >= off) v += u;
    }
    if (lane == 63) wsum[wid] = v;
    __syncthreads();
    if (tid < 16) {
        uint w0 = wsum[tid], w = w0;
        for (int off = 1; off < 16; off <<= 1) {
            uint u = __shfl_up(w, off);
            if ((int)tid >= off) w += u;
        }
        wsum[tid] = w - w0;
    }
    __syncthreads();
    uint excl = (v - key) + wsum[wid];
    uint gbase = excl >> 16, ebase = excl & 0xFFFFu;
    if (gt || (eq && ebase < tieM)) {
        uint pos = gbase + min(ebase, tieM);
        permL[pos] = base + tid;
        tvL[pos] = tanhf(svals[tid]);
    }
    __syncthreads();

    // pool: 32 threads/row x uint4 (8ch), 32 rows in flight, 16 serial iters
    {
        int rl = tid & 31, rg = tid >> 5;
        float a[8] = {0.f, 0.f, 0.f, 0.f, 0.f, 0.f, 0.f, 0.f};
        for (int it = 0; it < 16; it++) {
            int j = rg + it * 32;
            int row = permL[j];
            float tv = tvL[j];
            uint4 hv = *(const uint4*)&h2[((size_t)row << 8) + rl * 8];
            float f[8];
            unpk8(hv, f);
#pragma unroll
            for (int q = 0; q < 8; q++) {
                int cc = rl * 8 + q;
                a[q] += fmaxf(f[q] * sc[cc] + sh[cc], 0.f) * tv;
            }
        }
#pragma unroll
        for (int q = 0; q < 8; q++) part2[rg][rl * 8 + q] = a[q];
    }
    __syncthreads();
    if (tid < 256) {
        float s = 0.f;
#pragma unroll
        for (int gg = 0; gg < 32; gg++) s += part2[gg][tid];
        float sv = fmaxf(s * (1.f / (float)K2c), 0.f);
        rL[tid] = sv * Wlin[tid * 2 + 0];
        rL[256 + tid] = sv * Wlin[tid * 2 + 1];
    }
    __syncthreads();
    for (int off = 128; off; off >>= 1) {
        if (tid < off) { rL[tid] += rL[tid + off]; rL[256 + tid] += rL[256 + tid + off]; }
        __syncthreads();
    }
    if (tid == 0) {
        float o0 = rL[0] + blin[0], o1 = rL[256] + blin[1];
        float m = fmaxf(o0, o1);
        float e0 = expf(o0 - m), e1 = expf(o1 - m);
        float inv = 1.f / (e0 + e1);
        out[g * 2 + 0] = e0 * inv;
        out[g * 2 + 1] = e1 * inv;
    }
}

extern "C" void kernel_launch(void* const* d_in, const int* in_sizes, int n_in,
                              void* d_out, int out_size, void* d_ws, size_t ws_size,
                              hipStream_t stream) {
    const float* x      = (const float*)d_in[0];
    const int*   ei     = (const int*)d_in[1];
    const int*   src    = ei;
    const int*   tgt    = ei + Ee;
    const float* W1l    = (const float*)d_in[3];
    const float* b1l    = (const float*)d_in[4];
    const float* W1r    = (const float*)d_in[5];
    const float* bn1g   = (const float*)d_in[6];
    const float* bn1b   = (const float*)d_in[7];
    const float* p1Wrel = (const float*)d_in[8];
    const float* p1brel = (const float*)d_in[9];
    const float* p1Wroot= (const float*)d_in[10];
    const float* W2l    = (const float*)d_in[11];
    const float* b2l    = (const float*)d_in[12];
    const float* W2r    = (const float*)d_in[13];
    const float* bn2g   = (const float*)d_in[14];
    const float* bn2b   = (const float*)d_in[15];
    const float* p2Wrel = (const float*)d_in[16];
    const float* p2brel = (const float*)d_in[17];
    const float* p2Wroot= (const float*)d_in[18];
    const float* Wlin   = (const float*)d_in[19];
    const float* blin   = (const float*)d_in[20];
    float* out = (float*)d_out;
    char* ws = (char*)d_ws;

    size_t o = 0;
    auto A = [&](size_t b) { size_t r = o; o += (b + 255) & ~(size_t)255; return r; };
    size_t oH1   = A((size_t)Nn * H1c * 2);        // h1 bf16 (live through gemm2f)
    size_t oH2   = A((size_t)N1c * H2c * 2);       // h2 bf16
    size_t oCol1 = A((size_t)Nn * SLAB * 4);
    size_t oCol2 = A((size_t)N1c * SLAB * 4);
    size_t oWc1  = A((size_t)Nn * 4);
    size_t oR1   = A((size_t)Nn * 4);
    size_t oRoot1= A((size_t)Nn * 4);
    size_t oPerm1= A((size_t)N1c * 4);
    size_t oTv1  = A((size_t)N1c * 4);
    size_t oWc2  = A((size_t)N1c * 4);
    size_t oR2   = A((size_t)N1c * 4);
    size_t oRoot2= A((size_t)N1c * 4);
    size_t oDst  = A(768 * 8);
    size_t oWt1l = A(8192 * 2);
    size_t oWt1r = A(8192 * 2);
    size_t oWt2l = A(32768 * 2);
    size_t oWt2r = A(32768 * 2);
    (void)ws_size; (void)in_sizes; (void)n_in; (void)out_size;

    ushort* h1   = (ushort*)(ws + oH1);
    ushort* h2   = (ushort*)(ws + oH2);
    int* col1    = (int*)(ws + oCol1);
    int* col2    = (int*)(ws + oCol2);
    int* wc1     = (int*)(ws + oWc1);
    float* r1    = (float*)(ws + oR1);
    float* root1 = (float*)(ws + oRoot1);
    int* perm1   = (int*)(ws + oPerm1);
    float* tv1   = (float*)(ws + oTv1);
    int* wc2     = (int*)(ws + oWc2);
    float* r2    = (float*)(ws + oR2);
    float* root2 = (float*)(ws + oRoot2);
    double* dsum1= (double*)(ws + oDst);
    double* dsq1 = dsum1 + 128;
    double* dsum2= dsum1 + 256;
    double* dsq2 = dsum1 + 512;
    ushort* T1l  = (ushort*)(ws + oWt1l);
    ushort* T1r  = (ushort*)(ws + oWt1r);
    ushort* T2l  = (ushort*)(ws + oWt2l);
    ushort* T2r  = (ushort*)(ws + oWt2r);

    // 1. init zeros (wc1, BN stats)
    init_kernel<<<(INIT_TOTAL + 255) / 256, 256, 0, stream>>>(
        (int4*)wc1, (int4*)dsum1);

    // 2. fused: fill1 || weight transposes
    prep2_kernel<<<PREP2_TOTAL / 256, 256, 0, stream>>>(
        src, tgt, W1l, W1r, W2l, W2r, T1l, T1r, T2l, T2r, wc1, col1);

    // 3. fused agg1 + GEMM1 from f32 x (+ BN1 stats), full-K staged
    gemm1f_kernel<<<512, 512, 0, stream>>>(x, wc1, col1, T1l, T1r, b1l, h1,
                                           dsum1, dsq1);

    // 4. score1 full-grid (r1/root1), XCD-affine
    score_kernel<H1c><<<Nn / 32, 256, 0, stream>>>(h1, dsum1, dsq1, bn1g, bn1b, p1Wrel,
                                                   p1Wroot, r1, root1, Nn, NPGc);

    // 5. svals + radix select + fused layer2 CSR build, XCD-affine
    sel1_kernel<<<Bg, 1024, 0, stream>>>(r1, root1, wc1, col1, p1brel, perm1, tv1,
                                         wc2, col2);

    // 6. fused BN1-apply + agg2 + GEMM2 (+ BN2 stats), full-K A staged
    gemm2f_kernel<<<256, 512, 0, stream>>>(h1, perm1, tv1, dsum1, dsq1, bn1g, bn1b,
                                           wc2, col2, T2l, T2r, b2l, h2, dsum2, dsq2);

    // 7. score2 full-grid (r2/root2), XCD-affine
    score_kernel<H2c><<<N1c / 32, 256, 0, stream>>>(h2, dsum2, dsq2, bn2g, bn2b, p2Wrel,
                                                    p2Wroot, r2, root2, N1c, K1c);

    // 8. svals2 + select + pool + readout, XCD-affine
    sel2pool_kernel<<<Bg, 1024, 0, stream>>>(r2, root2, wc2, col2, p2brel, h2, dsum2,
                                             dsq2, bn2g, bn2b, Wlin, blin, out);
}